// Round 25
// baseline (3307.566 us; speedup 1.0000x reference)
//
#include <hip/hip_runtime.h>
#include <math.h>
#include <cstddef>

// ---------------- constants ----------------
constexpr int E = 256, H = 256, H3 = 768;
constexpr int GUH = 3072, GFC = 1024, DEC = 512;
constexpr int NNODES = 87381, LEAF0 = 21845, NLEAF = 65536;

using f16 = _Float16;
typedef __attribute__((ext_vector_type(8))) _Float16 f16x8;
typedef __attribute__((ext_vector_type(4))) _Float16 f16x4;
typedef __attribute__((ext_vector_type(4))) float f32x4;
typedef unsigned int u32;
typedef __attribute__((address_space(1))) const u32 gu32;
typedef __attribute__((address_space(3))) u32 lu32;

// fast transcendentals: v_exp_f32 / v_rcp_f32 based, ~1e-6 rel err
static __device__ __forceinline__ float frcp(float x) { return __builtin_amdgcn_rcpf(x); }
static __device__ __forceinline__ float sigf(float x) { return frcp(1.0f + __expf(-x)); }
static __device__ __forceinline__ float tanh_f(float x) {
    float e = __expf(fminf(2.0f * x, 30.0f));   // clamp avoids inf/inf
    return (e - 1.0f) * frcp(e + 1.0f);
}
static __device__ __forceinline__ void gload16(const void* g, void* l) {
    __builtin_amdgcn_global_load_lds((gu32*)g, (lu32*)l, 16, 0, 0);
}

// GArg + EPI semantics:
// out[m,n] = sum_k A0[m,k]B0[n,k] + sum_k A1[m,k]B1[n,k]  (K0/K1 mult of 32)
// EPI 0: +bias -> Cf f32 / Ch f16 (either or both)
// EPI 1: LSTM cell. B rows gate-interleaved: row m <-> gate=(m>>4)&3,
//        unit=(m>>7)*32+((m>>6)&1)*16+(m&15). Fragment j == gate. Writes
//        c (f16, level-local; SKIPPED when fin=1 — final step, c dead),
//        h (f16).
//        gst: store raw pre-bias acc (f16) at [row*N + permuted col] (t=0);
//        gin: add stored acc back before bias (t=5; same col formula).
//        RACE SAFETY: hb must differ from every A input (h double-buffered).
// EPI 2: fc-message: fcm[r,col] = cch[r,col] * sigmoid(xff[r>>2,col] + acc)
//        (xff is f16)
// A rows clamped to M-1 during staging. LDS bank-conflict swizzle: chunk
// c_phys = c_logical ^ ((row>>1)&3) on source addr and read addr.
// XCD-aware bijective block swizzle (m204); pair kernels use a per-XCD
// BALANCED split (each XCD gets contiguous chunks of BOTH sub-problems)
// when both sub-grid sizes are divisible by 8 (prevents L2 thrash).
// R25: 128x128/256thr tile ONLY — the m103/m105 tile-space data (128²=912
// vs 128x256=823 TF at the 2-barrier structure) applies now that the big
// dispatches are no longer byte-bound (R24 counters: HBM 12%, MfmaUtil 27%).
// CODEGEN RULE (R7/R15 lesson): kernel bodies stay fully inline with their
// __shared__ decls; never pass LDS pointers through helpers. Pair kernels
// select between two GArg by a uniform scalar copy only.
struct GArg {
    const f16 *A0 = nullptr, *B0 = nullptr, *A1 = nullptr, *B1 = nullptr;
    int la0 = 0, lb0 = 0, K0 = 0, la1 = 0, lb1 = 0, K1 = 0;
    const float* bias = nullptr;
    float* Cf = nullptr; f16* Ch = nullptr; int ldc = 0;              // EPI 0
    f16* cb = nullptr; f16* hb = nullptr;                             // EPI 1
    int HH = 0; int init = 0; int fin = 0;                            // EPI 1
    f16* gst = nullptr; const f16* gin = nullptr;                    // EPI 1 tok reuse
    const f16* xff = nullptr; const float* cch = nullptr; f16* fcm = nullptr; // EPI 2
    int M = 0, N = 0;
};

// ================= 128x128 tile, 256 thr (single) ==========================
template<int EPI>
__global__ __launch_bounds__(256) void gemm_one(GArg a)
{
    __shared__ f16 As[2][128 * 32];
    __shared__ f16 Bs[2][128 * 32];
    const int tid = threadIdx.x;

    const int gX = gridDim.x;
    const int nwg = gX * gridDim.y;
    const int orig = blockIdx.y * gX + blockIdx.x;
    const int q = nwg >> 3, r = nwg & 7;
    const int xcd = orig & 7, rem = orig >> 3;
    const int wgid = (xcd < r ? xcd * (q + 1) : r * (q + 1) + (xcd - r) * q) + rem;
    const int bx = wgid % gX, by = wgid / gX;

    const int m0 = by * 128, n0 = bx * 128;
    const int wave = tid >> 6, lane = tid & 63;
    const int wm = (wave >> 1) * 64, wn = (wave & 1) * 64;
    const int lr = lane & 15, kg = lane >> 4;
    const int px = kg ^ ((lr >> 1) & 3);

    f32x4 acc[4][4];
#pragma unroll
    for (int i = 0; i < 4; ++i)
#pragma unroll
        for (int j = 0; j < 4; ++j) acc[i][j] = (f32x4){0.f, 0.f, 0.f, 0.f};

    const int nt1 = a.K0 >> 5;
    const int nt = nt1 + (a.K1 >> 5);

    auto stage = [&](int t, int b) {
        const f16* Ap; const f16* Bp; int la, lb, k0;
        if (t < nt1) { Ap = a.A0; Bp = a.B0; la = a.la0; lb = a.lb0; k0 = t * 32; }
        else         { Ap = a.A1; Bp = a.B1; la = a.la1; lb = a.lb1; k0 = (t - nt1) * 32; }
#pragma unroll
        for (int v = 0; v < 2; ++v) {
            int idx = v * 256 + tid;
            int row = idx >> 2, cph = idx & 3;
            int clog = cph ^ ((row >> 1) & 3);
            int ar = m0 + row;
            if (ar >= a.M) ar = a.M - 1;
            gload16(Ap + (size_t)ar * la + k0 + clog * 8, &As[b][idx * 8]);
            gload16(Bp + (size_t)(n0 + row) * lb + k0 + clog * 8, &Bs[b][idx * 8]);
        }
    };

    stage(0, 0);
    for (int t = 0; t < nt; ++t) {
        __syncthreads();
        if (t + 1 < nt) stage(t + 1, (t + 1) & 1);
        const f16* as = As[t & 1];
        const f16* bs = Bs[t & 1];
        f16x8 af[4], bfr[4];
#pragma unroll
        for (int i = 0; i < 4; ++i) {
            af[i]  = *(const f16x8*)&as[(wm + i * 16 + lr) * 32 + px * 8];
            bfr[i] = *(const f16x8*)&bs[(wn + i * 16 + lr) * 32 + px * 8];
        }
#pragma unroll
        for (int i = 0; i < 4; ++i)
#pragma unroll
            for (int j = 0; j < 4; ++j)
                acc[i][j] = __builtin_amdgcn_mfma_f32_16x16x32_f16(af[i], bfr[j], acc[i][j], 0, 0, 0);
    }

    if constexpr (EPI == 0) {
#pragma unroll
        for (int i = 0; i < 4; ++i)
#pragma unroll
            for (int j = 0; j < 4; ++j) {
                int col = n0 + wn + j * 16 + lr;
                float bv = a.bias ? a.bias[col] : 0.f;
#pragma unroll
                for (int r = 0; r < 4; ++r) {
                    int rowg = m0 + wm + i * 16 + kg * 4 + r;
                    if (rowg < a.M) {
                        float v = acc[i][j][r] + bv;
                        if (a.Cf) a.Cf[(size_t)rowg * a.ldc + col] = v;
                        if (a.Ch) a.Ch[(size_t)rowg * a.ldc + col] = (f16)v;
                    }
                }
            }
    } else if constexpr (EPI == 1) {
        int ub = (n0 >> 2) + (wave & 1) * 16 + lr;
        int c0 = n0 + wn + lr;
        float b0 = a.bias[c0];
        float b1 = a.bias[c0 + 16];
        float b2 = a.bias[c0 + 32];
        float b3 = a.bias[c0 + 48];
#pragma unroll
        for (int i = 0; i < 4; ++i)
#pragma unroll
            for (int r = 0; r < 4; ++r) {
                int rowg = m0 + wm + i * 16 + kg * 4 + r;
                if (rowg < a.M) {
                    float ga0 = acc[i][0][r], ga1 = acc[i][1][r];
                    float ga2 = acc[i][2][r], ga3 = acc[i][3][r];
                    size_t gbase = (size_t)rowg * a.N + c0;
                    if (a.gst) {
                        a.gst[gbase]      = (f16)ga0;
                        a.gst[gbase + 16] = (f16)ga1;
                        a.gst[gbase + 32] = (f16)ga2;
                        a.gst[gbase + 48] = (f16)ga3;
                    }
                    if (a.gin) {
                        ga0 += (float)a.gin[gbase];
                        ga1 += (float)a.gin[gbase + 16];
                        ga2 += (float)a.gin[gbase + 32];
                        ga3 += (float)a.gin[gbase + 48];
                    }
                    float gi = ga0 + b0;
                    float gf = ga1 + b1;
                    float gg = ga2 + b2;
                    float go = ga3 + b3;
                    size_t off = (size_t)rowg * a.HH + ub;
                    float cn = sigf(gi) * tanh_f(gg);
                    if (!a.init) cn = fmaf(sigf(gf), (float)a.cb[off], cn);
                    if (!a.fin) a.cb[off] = (f16)cn;   // final step: c is dead
                    a.hb[off] = (f16)(sigf(go) * tanh_f(cn));
                }
            }
    } else {
#pragma unroll
        for (int i = 0; i < 4; ++i)
#pragma unroll
            for (int j = 0; j < 4; ++j) {
                int col = n0 + wn + j * 16 + lr;
#pragma unroll
                for (int r = 0; r < 4; ++r) {
                    int rowg = m0 + wm + i * 16 + kg * 4 + r;
                    if (rowg < a.M) {
                        float xv = (float)a.xff[(size_t)(rowg >> 2) * H + col];
                        float cv = a.cch[(size_t)rowg * H + col];
                        a.fcm[(size_t)rowg * H + col] =
                            (f16)(cv * sigf(xv + acc[i][j][r]));
                    }
                }
            }
    }
}

// ================= 128x128 tile, 256 thr (pair: u | f) =====================
template<int EPI>
__global__ __launch_bounds__(256) void gemm_pair(GArg u, GArg f, int split)
{
    __shared__ f16 As[2][128 * 32];
    __shared__ f16 Bs[2][128 * 32];
    const int tid = threadIdx.x;

    const int gX = gridDim.x, gY = gridDim.y;
    const int orig = blockIdx.y * gX + blockIdx.x;
    const int gXf = gX - split;
    const int nwgU = split * gY, nwgF = gXf * gY;

    int bx, by, isU;
    if (((nwgU | nwgF) & 7) == 0) {
        int cu = nwgU >> 3, cf = nwgF >> 3;
        int xcd = orig & 7, rem = orig >> 3;
        if (rem < cu) { int lid = xcd * cu + rem;        isU = 1; by = lid / split; bx = lid % split; }
        else          { int lid = xcd * cf + (rem - cu); isU = 0; by = lid / gXf;  bx = lid % gXf; }
    } else {
        const int nwg = gX * gY;
        const int q = nwg >> 3, r = nwg & 7;
        const int xcd = orig & 7, rem = orig >> 3;
        const int wgid = (xcd < r ? xcd * (q + 1) : r * (q + 1) + (xcd - r) * q) + rem;
        int bx0 = wgid % gX; by = wgid / gX;
        isU = (bx0 < split);
        bx = isU ? bx0 : bx0 - split;
    }
    const GArg a = isU ? u : f;        // uniform scalar select

    const int m0 = by * 128, n0 = bx * 128;
    const int wave = tid >> 6, lane = tid & 63;
    const int wm = (wave >> 1) * 64, wn = (wave & 1) * 64;
    const int lr = lane & 15, kg = lane >> 4;
    const int px = kg ^ ((lr >> 1) & 3);

    f32x4 acc[4][4];
#pragma unroll
    for (int i = 0; i < 4; ++i)
#pragma unroll
        for (int j = 0; j < 4; ++j) acc[i][j] = (f32x4){0.f, 0.f, 0.f, 0.f};

    const int nt1 = a.K0 >> 5;
    const int nt = nt1 + (a.K1 >> 5);

    auto stage = [&](int t, int b) {
        const f16* Ap; const f16* Bp; int la, lb, k0;
        if (t < nt1) { Ap = a.A0; Bp = a.B0; la = a.la0; lb = a.lb0; k0 = t * 32; }
        else         { Ap = a.A1; Bp = a.B1; la = a.la1; lb = a.lb1; k0 = (t - nt1) * 32; }
#pragma unroll
        for (int v = 0; v < 2; ++v) {
            int idx = v * 256 + tid;
            int row = idx >> 2, cph = idx & 3;
            int clog = cph ^ ((row >> 1) & 3);
            int ar = m0 + row;
            if (ar >= a.M) ar = a.M - 1;
            gload16(Ap + (size_t)ar * la + k0 + clog * 8, &As[b][idx * 8]);
            gload16(Bp + (size_t)(n0 + row) * lb + k0 + clog * 8, &Bs[b][idx * 8]);
        }
    };

    stage(0, 0);
    for (int t = 0; t < nt; ++t) {
        __syncthreads();
        if (t + 1 < nt) stage(t + 1, (t + 1) & 1);
        const f16* as = As[t & 1];
        const f16* bs = Bs[t & 1];
        f16x8 af[4], bfr[4];
#pragma unroll
        for (int i = 0; i < 4; ++i) {
            af[i]  = *(const f16x8*)&as[(wm + i * 16 + lr) * 32 + px * 8];
            bfr[i] = *(const f16x8*)&bs[(wn + i * 16 + lr) * 32 + px * 8];
        }
#pragma unroll
        for (int i = 0; i < 4; ++i)
#pragma unroll
            for (int j = 0; j < 4; ++j)
                acc[i][j] = __builtin_amdgcn_mfma_f32_16x16x32_f16(af[i], bfr[j], acc[i][j], 0, 0, 0);
    }

    if constexpr (EPI == 0) {
#pragma unroll
        for (int i = 0; i < 4; ++i)
#pragma unroll
            for (int j = 0; j < 4; ++j) {
                int col = n0 + wn + j * 16 + lr;
                float bv = a.bias ? a.bias[col] : 0.f;
#pragma unroll
                for (int r = 0; r < 4; ++r) {
                    int rowg = m0 + wm + i * 16 + kg * 4 + r;
                    if (rowg < a.M) {
                        float v = acc[i][j][r] + bv;
                        if (a.Cf) a.Cf[(size_t)rowg * a.ldc + col] = v;
                        if (a.Ch) a.Ch[(size_t)rowg * a.ldc + col] = (f16)v;
                    }
                }
            }
    } else {
        int ub = (n0 >> 2) + (wave & 1) * 16 + lr;
        int c0 = n0 + wn + lr;
        float b0 = a.bias[c0];
        float b1 = a.bias[c0 + 16];
        float b2 = a.bias[c0 + 32];
        float b3 = a.bias[c0 + 48];
#pragma unroll
        for (int i = 0; i < 4; ++i)
#pragma unroll
            for (int r = 0; r < 4; ++r) {
                int rowg = m0 + wm + i * 16 + kg * 4 + r;
                if (rowg < a.M) {
                    float ga0 = acc[i][0][r], ga1 = acc[i][1][r];
                    float ga2 = acc[i][2][r], ga3 = acc[i][3][r];
                    size_t gbase = (size_t)rowg * a.N + c0;
                    if (a.gst) {
                        a.gst[gbase]      = (f16)ga0;
                        a.gst[gbase + 16] = (f16)ga1;
                        a.gst[gbase + 32] = (f16)ga2;
                        a.gst[gbase + 48] = (f16)ga3;
                    }
                    if (a.gin) {
                        ga0 += (float)a.gin[gbase];
                        ga1 += (float)a.gin[gbase + 16];
                        ga2 += (float)a.gin[gbase + 32];
                        ga3 += (float)a.gin[gbase + 48];
                    }
                    float gi = ga0 + b0;
                    float gf = ga1 + b1;
                    float gg = ga2 + b2;
                    float go = ga3 + b3;
                    size_t off = (size_t)rowg * a.HH + ub;
                    float cn = sigf(gi) * tanh_f(gg);
                    if (!a.init) cn = fmaf(sigf(gf), (float)a.cb[off], cn);
                    if (!a.fin) a.cb[off] = (f16)cn;   // final step: c is dead
                    a.hb[off] = (f16)(sigf(go) * tanh_f(cn));
                }
            }
    }
}

// ---------------- f32 tiled NT GEMM (prep only: folded weight) ----------------
__global__ __launch_bounds__(256) void gemm_nt_f32(
    const float* __restrict__ A, int lda,
    const float* __restrict__ B, int ldb,
    float* __restrict__ C, int ldc, int M, int N, int K)
{
    __shared__ float As[16][128];
    __shared__ float Bs[16][128];
    const int m0 = blockIdx.y * 128, n0 = blockIdx.x * 128;
    const int tid = threadIdx.x;
    const int tx = tid & 15, ty = tid >> 4;
    float acc[8][8];
#pragma unroll
    for (int i = 0; i < 8; ++i)
#pragma unroll
        for (int j = 0; j < 8; ++j) acc[i][j] = 0.0f;
    for (int k0 = 0; k0 < K; k0 += 16) {
#pragma unroll
        for (int v = 0; v < 2; ++v) {
            int idx = tid + v * 256;
            int row = idx >> 2, c4 = idx & 3;
            float4 av = make_float4(0, 0, 0, 0);
            int gm = m0 + row;
            if (gm < M) av = *(const float4*)&A[(size_t)gm * lda + k0 + c4 * 4];
            As[c4 * 4 + 0][row] = av.x; As[c4 * 4 + 1][row] = av.y;
            As[c4 * 4 + 2][row] = av.z; As[c4 * 4 + 3][row] = av.w;
            float4 bv = make_float4(0, 0, 0, 0);
            int gn = n0 + row;
            if (gn < N) bv = *(const float4*)&B[(size_t)gn * ldb + k0 + c4 * 4];
            Bs[c4 * 4 + 0][row] = bv.x; Bs[c4 * 4 + 1][row] = bv.y;
            Bs[c4 * 4 + 2][row] = bv.z; Bs[c4 * 4 + 3][row] = bv.w;
        }
        __syncthreads();
#pragma unroll
        for (int kk = 0; kk < 16; ++kk) {
            float4 a0 = *(const float4*)&As[kk][ty * 8];
            float4 a1 = *(const float4*)&As[kk][ty * 8 + 4];
            float4 b0 = *(const float4*)&Bs[kk][tx * 8];
            float4 b1 = *(const float4*)&Bs[kk][tx * 8 + 4];
            float av[8] = { a0.x,a0.y,a0.z,a0.w,a1.x,a1.y,a1.z,a1.w };
            float bv[8] = { b0.x,b0.y,b0.z,b0.w,b1.x,b1.y,b1.z,b1.w };
#pragma unroll
            for (int i = 0; i < 8; ++i)
#pragma unroll
                for (int j = 0; j < 8; ++j)
                    acc[i][j] = fmaf(av[i], bv[j], acc[i][j]);
        }
        __syncthreads();
    }
#pragma unroll
    for (int i = 0; i < 8; ++i) {
        int gm = m0 + ty * 8 + i;
        if (gm >= M) break;
#pragma unroll
        for (int j = 0; j < 8; ++j) {
            int gn = n0 + tx * 8 + j;
            if (gn < N) C[(size_t)gm * ldc + gn] = acc[i][j];
        }
    }
}

// ---------------- elementwise / prep kernels ----------------

// leaves: iou f16 [count,768] -> h f16, c f32 (pointers pre-offset)
__global__ __launch_bounds__(256) void leaf_apply(
    const f16* __restrict__ iou, f16* __restrict__ hh, float* __restrict__ c,
    int count)
{
    int idx = blockIdx.x * 256 + threadIdx.x;
    int tot = count * (H / 4);
    if (idx >= tot) return;
    int row = idx >> 6;
    int c4 = (idx & 63) * 4;
    const f16* r = iou + (size_t)row * H3;
    f16x4 vi = *(const f16x4*)&r[c4];
    f16x4 vo = *(const f16x4*)&r[H + c4];
    f16x4 vu = *(const f16x4*)&r[2 * H + c4];
    size_t off = (size_t)row * H + c4;
    float cc[4]; f16x4 hq;
#pragma unroll
    for (int j = 0; j < 4; ++j) {
        cc[j] = sigf((float)vi[j]) * tanh_f((float)vu[j]);
        hq[j] = (f16)(sigf((float)vo[j]) * tanh_f(cc[j]));
    }
    *(float4*)&c[off] = make_float4(cc[0], cc[1], cc[2], cc[3]);
    *(f16x4*)&hh[off] = hq;
}

// internal apply: all f16 inputs; h f16 + c f32 out (pointers pre-offset)
__global__ __launch_bounds__(256) void node_apply(
    const f16* __restrict__ xiou, const f16* __restrict__ h_uh,
    const f16* __restrict__ hfc, f16* __restrict__ hh, float* __restrict__ c,
    int Cn)
{
    int idx = blockIdx.x * 256 + threadIdx.x;
    int tot = Cn * (H / 4);
    if (idx >= tot) return;
    int row = idx >> 6;
    int c4 = (idx & 63) * 4;
    const f16* xr = xiou + (size_t)row * H3;
    const f16* ur = h_uh + (size_t)row * H3;
    f16x4 xi = *(const f16x4*)&xr[c4];
    f16x4 xo = *(const f16x4*)&xr[H + c4];
    f16x4 xu = *(const f16x4*)&xr[2 * H + c4];
    f16x4 ui = *(const f16x4*)&ur[c4];
    f16x4 uo = *(const f16x4*)&ur[H + c4];
    f16x4 uu = *(const f16x4*)&ur[2 * H + c4];
    f16x4 fv = *(const f16x4*)&hfc[(size_t)row * H + c4];
    size_t off = (size_t)row * H + c4;
    float cc[4]; f16x4 hq;
#pragma unroll
    for (int j = 0; j < 4; ++j) {
        float iv = (float)xi[j] + (float)ui[j];
        float ov = (float)xo[j] + (float)uo[j];
        float uv = (float)xu[j] + (float)uu[j];
        float cv = sigf(iv) * tanh_f(uv) + (float)fv[j];
        cc[j] = cv;
        hq[j] = (f16)(sigf(ov) * tanh_f(cv));
    }
    *(float4*)&c[off] = make_float4(cc[0], cc[1], cc[2], cc[3]);
    *(f16x4*)&hh[off] = hq;
}

__global__ __launch_bounds__(256) void bias_sum(
    const float* __restrict__ a, const float* __restrict__ b, float* __restrict__ o, int n)
{
    int i = blockIdx.x * 256 + threadIdx.x;
    if (i < n) o[i] = a[i] + b[i];
}

__global__ __launch_bounds__(256) void cvt_f16(
    const float* __restrict__ in, f16* __restrict__ out, int n)
{
    int idx = blockIdx.x * 256 + threadIdx.x;
    if (idx * 4 >= n) return;
    float4 v = *(const float4*)&in[idx * 4];
    f16x4 o; o[0] = (f16)v.x; o[1] = (f16)v.y; o[2] = (f16)v.z; o[3] = (f16)v.w;
    *(f16x4*)&out[idx * 4] = o;
}

__global__ __launch_bounds__(256) void permute_cvt(
    const float* __restrict__ src, f16* __restrict__ dst, int HH, int K, int tot4)
{
    int idx = blockIdx.x * 256 + threadIdx.x;
    if (idx >= tot4) return;
    int kq = K >> 2;
    int m = idx / kq;
    int k4 = (idx - m * kq) * 4;
    int gate = (m >> 4) & 3;
    int unit = (m >> 7) * 32 + ((m >> 6) & 1) * 16 + (m & 15);
    float4 v = *(const float4*)&src[(size_t)(gate * HH + unit) * K + k4];
    f16x4 o; o[0] = (f16)v.x; o[1] = (f16)v.y; o[2] = (f16)v.z; o[3] = (f16)v.w;
    *(f16x4*)&dst[(size_t)m * K + k4] = o;
}

__global__ __launch_bounds__(256) void permute_bias(
    const float* __restrict__ src, float* __restrict__ dst, int HH, int n)
{
    int m = blockIdx.x * 256 + threadIdx.x;
    if (m >= n) return;
    int gate = (m >> 4) & 3;
    int unit = (m >> 7) * 32 + ((m >> 6) & 1) * 16 + (m & 15);
    dst[m] = src[gate * HH + unit];
}

__global__ __launch_bounds__(256) void transpose_f32(
    const float* __restrict__ in, float* __restrict__ out)
{
    int idx = blockIdx.x * 256 + threadIdx.x;
    if (idx >= H3 * E) return;
    int r = idx >> 8, c = idx & 255;
    out[(size_t)c * H3 + r] = in[idx];
}

__global__ __launch_bounds__(256) void ln_tanh(
    float* __restrict__ y, const float* __restrict__ g, const float* __restrict__ b,
    int Nrows)
{
    int wave = threadIdx.x >> 6;
    int lane = threadIdx.x & 63;
    int row = blockIdx.x * 4 + wave;
    if (row >= Nrows) return;
    float* yr = y + (size_t)row * DEC;
    float4 v0 = *(const float4*)&yr[lane * 8];
    float4 v1 = *(const float4*)&yr[lane * 8 + 4];
    float s = v0.x + v0.y + v0.z + v0.w + v1.x + v1.y + v1.z + v1.w;
    float s2 = v0.x * v0.x + v0.y * v0.y + v0.z * v0.z + v0.w * v0.w +
               v1.x * v1.x + v1.y * v1.y + v1.z * v1.z + v1.w * v1.w;
#pragma unroll
    for (int off = 32; off; off >>= 1) {
        s += __shfl_xor(s, off);
        s2 += __shfl_xor(s2, off);
    }
    float m = s * (1.0f / DEC);
    float var = s2 * (1.0f / DEC) - m * m;
    float rstd = rsqrtf(var + 1e-5f);
    float vals[8] = { v0.x,v0.y,v0.z,v0.w,v1.x,v1.y,v1.z,v1.w };
    float o[8];
#pragma unroll
    for (int j = 0; j < 8; ++j) {
        int colj = lane * 8 + j;
        o[j] = tanh_f((vals[j] - m) * rstd * g[colj] + b[colj]);
    }
    *(float4*)&yr[lane * 8] = make_float4(o[0], o[1], o[2], o[3]);
    *(float4*)&yr[lane * 8 + 4] = make_float4(o[4], o[5], o[6], o[7]);
}

// ---------------- host ----------------
extern "C" void kernel_launch(void* const* d_in, const int* in_sizes, int n_in,
                              void* d_out, int out_size, void* d_ws, size_t ws_size,
                              hipStream_t stream)
{
    (void)in_sizes; (void)n_in; (void)out_size;
    const float* embed   = (const float*)d_in[0];
    const float* W_iou_w = (const float*)d_in[1];
    const float* W_iou_b = (const float*)d_in[2];
    const float* U_iou_w = (const float*)d_in[3];
    const float* W_f_w   = (const float*)d_in[4];
    const float* W_f_b   = (const float*)d_in[5];
    const float* U_f_w   = (const float*)d_in[6];
    const float* uh_wih  = (const float*)d_in[7];
    const float* uh_whh  = (const float*)d_in[8];
    const float* uh_bih  = (const float*)d_in[9];
    const float* uh_bhh  = (const float*)d_in[10];
    const float* fc_wih  = (const float*)d_in[11];
    const float* fc_whh  = (const float*)d_in[12];
    const float* fc_bih  = (const float*)d_in[13];
    const float* fc_bhh  = (const float*)d_in[14];
    const float* out_w   = (const float*)d_in[15];
    const float* out_b   = (const float*)d_in[16];
    const float* ln_g    = (const float*)d_in[17];
    const float* ln_b    = (const float*)d_in[18];

    float* out  = (float*)d_out;
    float* cbuf = out;

    float* ws = (float*)d_ws;
    size_t o = 0;
    f16* embed_h = (f16*)(ws + o); o += (size_t)NNODES * E / 2;
    f16* hbuf_h  = (f16*)(ws + o); o += (size_t)NNODES * H / 2;
    f16* wiou_h  = (f16*)(ws + o); o += (size_t)H3 * E / 2;
    f16* wf_h    = (f16*)(ws + o); o += (size_t)H * E / 2;
    f16* uf_h    = (f16*)(ws + o); o += (size_t)H * H / 2;
    f16* wih_p   = (f16*)(ws + o); o += (size_t)GUH * H3 / 2;
    f16* whh_p   = (f16*)(ws + o); o += (size_t)GUH * H3 / 2;
    f16* fih_p   = (f16*)(ws + o); o += (size_t)GFC * H / 2;
    f16* fhh_p   = (f16*)(ws + o); o += (size_t)GFC * H / 2;
    f16* ow_h    = (f16*)(ws + o); o += (size_t)DEC * H / 2;
    f16* fold_p  = (f16*)(ws + o); o += (size_t)GUH * E / 2;
    float* fold_f = ws + o; o += (size_t)GUH * E;
    float* Ut     = ws + o; o += (size_t)E * H3;
    float* bsu    = ws + o; o += GUH;
    float* bsf    = ws + o; o += GFC;
    float* pbu    = ws + o; o += GUH;
    float* pbf    = ws + o; o += GFC;

    // per-chunk f32 words/row:
    // xiou_h 384 + xf_h 128 + gbuf 3072 + hfc0 128 + hfc1 128 + cfc 128
    // + huh0 384 + huh1 384 + c_uh 384 + fcm_h 512 = 5632
    size_t avail = ws_size / 4;
    long long room = (long long)avail - (long long)o - 8192;
    long long Cl = room / 5632;
    int C;
    if (Cl >= 16384) C = 16384;
    else if (Cl <= 256) C = 256;
    else C = (int)((Cl / 256) * 256);

    f16*   xiou_h = (f16*)(ws + o); o += (size_t)C * H3 / 2;
    f16*   xf_h   = (f16*)(ws + o); o += (size_t)C * H / 2;
    float* gbuf   = ws + o; o += (size_t)4 * C * H3;   // leaf iou f16 region; later tok store
    f16*   hfc0   = (f16*)(ws + o); o += (size_t)C * H / 2;
    f16*   hfc1   = (f16*)(ws + o); o += (size_t)C * H / 2;
    f16*   cfc    = (f16*)(ws + o); o += (size_t)C * H / 2;   // f16 level-local c
    f16*   huh0   = (f16*)(ws + o); o += (size_t)C * H3 / 2;
    f16*   huh1   = (f16*)(ws + o); o += (size_t)C * H3 / 2;
    f16*   c_uh   = (f16*)(ws + o); o += (size_t)C * H3 / 2;  // f16 level-local c
    f16*   fcm_h  = (f16*)(ws + o); o += (size_t)4 * C * H / 2;

    f16* huh[2] = { huh0, huh1 };
    f16* hfc[2] = { hfc0, hfc1 };

    // leaf iou (f16) and tok_ih stores (f16) carved from gbuf:
    f16* leaf_h = (f16*)gbuf;                              // [4C x 768] f16
    f16* toku   = (f16*)gbuf;                              // [C x 3072] f16 (after leaves)
    f16* tokf   = (f16*)(gbuf + (size_t)C * 1536);         // [C x 1024] f16

    // R25: all GEMMs on the 128x128/256thr tile (m103/m105: best at the
    // 2-barrier structure; big dispatches are no longer byte-bound).
    auto L0 = [&](const GArg& a) {
        gemm_one<0><<<dim3(a.N / 128, (a.M + 127) / 128), 256, 0, stream>>>(a);
    };
    auto P0 = [&](const GArg& u, const GArg& f) {
        gemm_pair<0><<<dim3(u.N / 128 + f.N / 128, (u.M + 127) / 128), 256, 0, stream>>>(u, f, u.N / 128);
    };
    auto P1 = [&](const GArg& u, const GArg& f) {
        gemm_pair<1><<<dim3(u.N / 128 + f.N / 128, (u.M + 127) / 128), 256, 0, stream>>>(u, f, u.N / 128);
    };

    // ---- prep ----
    auto CVT = [&](const float* s, f16* dv, int n) {
        cvt_f16<<<(n / 4 + 255) / 256, 256, 0, stream>>>(s, dv, n);
    };
    CVT(embed, embed_h, NNODES * E);
    CVT(W_iou_w, wiou_h, H3 * E);
    CVT(W_f_w, wf_h, H * E);
    CVT(U_f_w, uf_h, H * H);
    CVT(out_w, ow_h, DEC * H);
    permute_cvt<<<(GUH * H3 / 4 + 255) / 256, 256, 0, stream>>>(uh_wih, wih_p, H3, H3, GUH * H3 / 4);
    permute_cvt<<<(GUH * H3 / 4 + 255) / 256, 256, 0, stream>>>(uh_whh, whh_p, H3, H3, GUH * H3 / 4);
    permute_cvt<<<(GFC * H / 4 + 255) / 256, 256, 0, stream>>>(fc_wih, fih_p, H, H, GFC * H / 4);
    permute_cvt<<<(GFC * H / 4 + 255) / 256, 256, 0, stream>>>(fc_whh, fhh_p, H, H, GFC * H / 4);
    bias_sum<<<(GUH + 255) / 256, 256, 0, stream>>>(uh_bih, uh_bhh, bsu, GUH);
    bias_sum<<<(GFC + 255) / 256, 256, 0, stream>>>(fc_bih, fc_bhh, bsf, GFC);
    permute_bias<<<(GUH + 255) / 256, 256, 0, stream>>>(bsu, pbu, H3, GUH);
    permute_bias<<<(GFC + 255) / 256, 256, 0, stream>>>(bsf, pbf, H, GFC);
    transpose_f32<<<(H3 * E + 255) / 256, 256, 0, stream>>>(U_iou_w, Ut);
    {
        dim3 grid(E / 128, GUH / 128);
        gemm_nt_f32<<<grid, 256, 0, stream>>>(uh_wih, H3, Ut, H3, fold_f, E, GUH, E, H3);
        permute_cvt<<<(GUH * E / 4 + 255) / 256, 256, 0, stream>>>(fold_f, fold_p, H3, E, GUH * E / 4);
    }

    // ---- leaves (iou in f16) ----
    for (int ls = 0; ls < NLEAF; ls += 4 * C) {
        int Ln = NLEAF - ls < 4 * C ? NLEAF - ls : 4 * C;
        GArg a{};
        a.A0 = embed_h + (size_t)(LEAF0 + ls) * E; a.la0 = E;
        a.B0 = wiou_h; a.lb0 = E; a.K0 = E;
        a.bias = W_iou_b; a.Ch = leaf_h; a.ldc = H3; a.M = Ln; a.N = H3;
        L0(a);
        leaf_apply<<<(Ln * 64 + 255) / 256, 256, 0, stream>>>(
            leaf_h, hbuf_h + (size_t)(LEAF0 + ls) * H, cbuf + (size_t)(LEAF0 + ls) * H, Ln);
    }

    // ---- levels, deepest internal -> root ----
    const int counts[8] = { 1, 4, 16, 64, 256, 1024, 4096, 16384 };
    const int offs[8]   = { 0, 1, 5, 21, 85, 341, 1365, 5461 };
    for (int d = 7; d >= 0; --d) {
        int n = counts[d], start = offs[d];
        for (int s = 0; s < n; s += C) {
            int Cn = n - s < C ? n - s : C;
            int sa = start + s;
            int cst = 4 * sa + 1;

            // x projections: iou | f merged (f16 shadows only)
            {
                GArg u{};
                u.A0 = embed_h + (size_t)sa * E; u.la0 = E;
                u.B0 = wiou_h; u.lb0 = E; u.K0 = E;
                u.bias = W_iou_b; u.Ch = xiou_h; u.ldc = H3;
                u.M = Cn; u.N = H3;
                GArg f = u;
                f.B0 = wf_h; f.bias = W_f_b; f.Ch = xf_h; f.ldc = H; f.N = H;
                P0(u, f);
            }
            // fc messages (GEMM + fc_msg fused; x_f read f16)
            {
                GArg a{};
                a.A0 = hbuf_h + (size_t)cst * H; a.la0 = H;
                a.B0 = uf_h; a.lb0 = H; a.K0 = H;
                a.xff = xf_h; a.cch = cbuf + (size_t)cst * H; a.fcm = fcm_h;
                a.M = 4 * Cn; a.N = H;
                gemm_one<2><<<dim3(H / 128, (a.M + 127) / 128), 256, 0, stream>>>(a);
            }
            // 6 LSTM steps; uh | fc merged per step, h double-buffered:
            // step t reads h[(t+1)&1], writes h[t&1]. t=0 stores tok_ih (f16);
            // t=5 adds it back (K halved), skips the dead c-write (fin=1).
            for (int t = 0; t <= 5; ++t) {
                int wb = t & 1, rb = (t + 1) & 1;

                GArg u{};
                u.bias = pbu; u.cb = c_uh; u.hb = huh[wb]; u.HH = H3;
                u.M = Cn; u.N = GUH;
                if (t == 0) {
                    u.A0 = xiou_h; u.la0 = H3; u.B0 = wih_p; u.lb0 = H3; u.K0 = H3;
                    u.init = 1;
                    u.gst = toku;
                } else if (t <= 4) {
                    u.A0 = hbuf_h + (size_t)(cst + t - 1) * H; u.la0 = 4 * H;
                    u.B0 = fold_p; u.lb0 = E; u.K0 = E;
                    u.A1 = huh[rb]; u.la1 = H3; u.B1 = whh_p; u.lb1 = H3; u.K1 = H3;
                } else {
                    u.A0 = huh[rb]; u.la0 = H3; u.B0 = whh_p; u.lb0 = H3; u.K0 = H3;
                    u.gin = toku;
                    u.fin = 1;
                }

                GArg f{};
                f.bias = pbf; f.cb = cfc; f.hb = hfc[wb]; f.HH = H;
                f.M = Cn; f.N = GFC;
                if (t == 0) {
                    f.A0 = xf_h; f.la0 = H; f.B0 = fih_p; f.lb0 = H; f.K0 = H;
                    f.init = 1;
                    f.gst = tokf;
                } else if (t <= 4) {
                    f.A0 = fcm_h + (size_t)(t - 1) * H; f.la0 = 4 * H;
                    f.B0 = fih_p; f.lb0 = H; f.K0 = H;
                    f.A1 = hfc[rb]; f.la1 = H; f.B1 = fhh_p; f.lb1 = H; f.K1 = H;
                } else {
                    f.A0 = hfc[rb]; f.la0 = H; f.B0 = fhh_p; f.lb0 = H; f.K0 = H;
                    f.gin = tokf;
                    f.fin = 1;
                }
                P1(u, f);
            }
            // apply node func (f16 inputs; t=5 wrote huh[1]/hfc[1])
            node_apply<<<(Cn * 64 + 255) / 256, 256, 0, stream>>>(
                xiou_h, huh[1], hfc[1],
                hbuf_h + (size_t)sa * H, cbuf + (size_t)sa * H, Cn);
        }
    }

    // ---- output projection (reads only ws; cbuf is dead) + LN/tanh ----
    {
        GArg a{};
        a.A0 = hbuf_h; a.la0 = H; a.B0 = ow_h; a.lb0 = H; a.K0 = H;
        a.bias = out_b; a.Cf = out; a.ldc = DEC; a.M = NNODES; a.N = DEC;
        L0(a);
    }
    ln_tanh<<<(NNODES + 3) / 4, 256, 0, stream>>>(out, ln_g, ln_b, NNODES);
}

// Round 26
// 3146.533 us; speedup vs baseline: 1.0512x; 1.0512x over previous
//
#include <hip/hip_runtime.h>
#include <math.h>
#include <cstddef>

// ---------------- constants ----------------
constexpr int E = 256, H = 256, H3 = 768;
constexpr int GUH = 3072, GFC = 1024, DEC = 512;
constexpr int NNODES = 87381, LEAF0 = 21845, NLEAF = 65536;

using f16 = _Float16;
typedef __attribute__((ext_vector_type(8))) _Float16 f16x8;
typedef __attribute__((ext_vector_type(4))) _Float16 f16x4;
typedef __attribute__((ext_vector_type(4))) float f32x4;
typedef unsigned int u32;
typedef __attribute__((address_space(1))) const u32 gu32;
typedef __attribute__((address_space(3))) u32 lu32;

// fast transcendentals: v_exp_f32 / v_rcp_f32 based, ~1e-6 rel err
static __device__ __forceinline__ float frcp(float x) { return __builtin_amdgcn_rcpf(x); }
static __device__ __forceinline__ float sigf(float x) { return frcp(1.0f + __expf(-x)); }
static __device__ __forceinline__ float tanh_f(float x) {
    float e = __expf(fminf(2.0f * x, 30.0f));   // clamp avoids inf/inf
    return (e - 1.0f) * frcp(e + 1.0f);
}
static __device__ __forceinline__ void gload16(const void* g, void* l) {
    __builtin_amdgcn_global_load_lds((gu32*)g, (lu32*)l, 16, 0, 0);
}

// GArg + EPI semantics:
// out[m,n] = sum_k A0[m,k]B0[n,k] + sum_k A1[m,k]B1[n,k]  (K0/K1 mult of 32)
// EPI 0: +bias -> Cf f32 / Ch f16 (either or both)
// EPI 1: LSTM cell. B rows gate-interleaved: row m <-> gate=(m>>4)&3,
//        unit=(m>>7)*32+((m>>6)&1)*16+(m&15). Fragment j == gate. Writes
//        c (f16, level-local; SKIPPED when fin=1 — final step, c dead),
//        h (f16).
//        gvb: constant per-column add (folded-bias) applied BEFORE gst —
//             so the stored tok equals the true x_iou@Wih^T (R26 fold2).
//        gst: store raw acc(+gvb) (f16) at [row*N + permuted col] (t=0);
//        gin: add stored acc back before bias (t=5; same col formula).
//        RACE SAFETY: hb must differ from every A input (h double-buffered).
// EPI 2: fc-message: fcm[r,col] = cch[r,col] * sigmoid(xff[r>>2,col] + acc)
//        (xff is f16)
// A rows clamped to M-1 during staging. LDS bank-conflict swizzle: chunk
// c_phys = c_logical ^ ((row>>1)&3) on source addr and read addr.
// XCD-aware bijective block swizzle (m204); pair kernels use a per-XCD
// BALANCED split (each XCD gets contiguous chunks of BOTH sub-problems)
// when both sub-grid sizes are divisible by 8 (prevents L2 thrash).
// R25 LESSON: 128x128-only routing REGRESSED (FETCH +16%, occupancy -25%);
// the 128x256/512thr tile stays for M>=8192 (B-reuse dominates here).
// CODEGEN RULE (R7/R15 lesson): kernel bodies stay fully inline with their
// __shared__ decls; never pass LDS pointers through helpers. Pair kernels
// select between two GArg by a uniform scalar copy only.
struct GArg {
    const f16 *A0 = nullptr, *B0 = nullptr, *A1 = nullptr, *B1 = nullptr;
    int la0 = 0, lb0 = 0, K0 = 0, la1 = 0, lb1 = 0, K1 = 0;
    const float* bias = nullptr;
    float* Cf = nullptr; f16* Ch = nullptr; int ldc = 0;              // EPI 0
    f16* cb = nullptr; f16* hb = nullptr;                             // EPI 1
    int HH = 0; int init = 0; int fin = 0;                            // EPI 1
    const float* gvb = nullptr;                                       // EPI 1 folded bias
    f16* gst = nullptr; const f16* gin = nullptr;                    // EPI 1 tok reuse
    const f16* xff = nullptr; const float* cch = nullptr; f16* fcm = nullptr; // EPI 2
    int M = 0, N = 0;
};

// ================= 128x128 tile, 256 thr (single) ==========================
template<int EPI>
__global__ __launch_bounds__(256) void gemm_one(GArg a)
{
    __shared__ f16 As[2][128 * 32];
    __shared__ f16 Bs[2][128 * 32];
    const int tid = threadIdx.x;

    const int gX = gridDim.x;
    const int nwg = gX * gridDim.y;
    const int orig = blockIdx.y * gX + blockIdx.x;
    const int q = nwg >> 3, r = nwg & 7;
    const int xcd = orig & 7, rem = orig >> 3;
    const int wgid = (xcd < r ? xcd * (q + 1) : r * (q + 1) + (xcd - r) * q) + rem;
    const int bx = wgid % gX, by = wgid / gX;

    const int m0 = by * 128, n0 = bx * 128;
    const int wave = tid >> 6, lane = tid & 63;
    const int wm = (wave >> 1) * 64, wn = (wave & 1) * 64;
    const int lr = lane & 15, kg = lane >> 4;
    const int px = kg ^ ((lr >> 1) & 3);

    f32x4 acc[4][4];
#pragma unroll
    for (int i = 0; i < 4; ++i)
#pragma unroll
        for (int j = 0; j < 4; ++j) acc[i][j] = (f32x4){0.f, 0.f, 0.f, 0.f};

    const int nt1 = a.K0 >> 5;
    const int nt = nt1 + (a.K1 >> 5);

    auto stage = [&](int t, int b) {
        const f16* Ap; const f16* Bp; int la, lb, k0;
        if (t < nt1) { Ap = a.A0; Bp = a.B0; la = a.la0; lb = a.lb0; k0 = t * 32; }
        else         { Ap = a.A1; Bp = a.B1; la = a.la1; lb = a.lb1; k0 = (t - nt1) * 32; }
#pragma unroll
        for (int v = 0; v < 2; ++v) {
            int idx = v * 256 + tid;
            int row = idx >> 2, cph = idx & 3;
            int clog = cph ^ ((row >> 1) & 3);
            int ar = m0 + row;
            if (ar >= a.M) ar = a.M - 1;
            gload16(Ap + (size_t)ar * la + k0 + clog * 8, &As[b][idx * 8]);
            gload16(Bp + (size_t)(n0 + row) * lb + k0 + clog * 8, &Bs[b][idx * 8]);
        }
    };

    stage(0, 0);
    for (int t = 0; t < nt; ++t) {
        __syncthreads();
        if (t + 1 < nt) stage(t + 1, (t + 1) & 1);
        const f16* as = As[t & 1];
        const f16* bs = Bs[t & 1];
        f16x8 af[4], bfr[4];
#pragma unroll
        for (int i = 0; i < 4; ++i) {
            af[i]  = *(const f16x8*)&as[(wm + i * 16 + lr) * 32 + px * 8];
            bfr[i] = *(const f16x8*)&bs[(wn + i * 16 + lr) * 32 + px * 8];
        }
#pragma unroll
        for (int i = 0; i < 4; ++i)
#pragma unroll
            for (int j = 0; j < 4; ++j)
                acc[i][j] = __builtin_amdgcn_mfma_f32_16x16x32_f16(af[i], bfr[j], acc[i][j], 0, 0, 0);
    }

    if constexpr (EPI == 0) {
#pragma unroll
        for (int i = 0; i < 4; ++i)
#pragma unroll
            for (int j = 0; j < 4; ++j) {
                int col = n0 + wn + j * 16 + lr;
                float bv = a.bias ? a.bias[col] : 0.f;
#pragma unroll
                for (int r = 0; r < 4; ++r) {
                    int rowg = m0 + wm + i * 16 + kg * 4 + r;
                    if (rowg < a.M) {
                        float v = acc[i][j][r] + bv;
                        if (a.Cf) a.Cf[(size_t)rowg * a.ldc + col] = v;
                        if (a.Ch) a.Ch[(size_t)rowg * a.ldc + col] = (f16)v;
                    }
                }
            }
    } else if constexpr (EPI == 1) {
        int ub = (n0 >> 2) + (wave & 1) * 16 + lr;
        int c0 = n0 + wn + lr;
        float b0 = a.bias[c0];
        float b1 = a.bias[c0 + 16];
        float b2 = a.bias[c0 + 32];
        float b3 = a.bias[c0 + 48];
        float v0 = 0.f, v1 = 0.f, v2 = 0.f, v3 = 0.f;
        if (a.gvb) {
            v0 = a.gvb[c0];      v1 = a.gvb[c0 + 16];
            v2 = a.gvb[c0 + 32]; v3 = a.gvb[c0 + 48];
        }
#pragma unroll
        for (int i = 0; i < 4; ++i)
#pragma unroll
            for (int r = 0; r < 4; ++r) {
                int rowg = m0 + wm + i * 16 + kg * 4 + r;
                if (rowg < a.M) {
                    float ga0 = acc[i][0][r] + v0, ga1 = acc[i][1][r] + v1;
                    float ga2 = acc[i][2][r] + v2, ga3 = acc[i][3][r] + v3;
                    size_t gbase = (size_t)rowg * a.N + c0;
                    if (a.gst) {
                        a.gst[gbase]      = (f16)ga0;
                        a.gst[gbase + 16] = (f16)ga1;
                        a.gst[gbase + 32] = (f16)ga2;
                        a.gst[gbase + 48] = (f16)ga3;
                    }
                    if (a.gin) {
                        ga0 += (float)a.gin[gbase];
                        ga1 += (float)a.gin[gbase + 16];
                        ga2 += (float)a.gin[gbase + 32];
                        ga3 += (float)a.gin[gbase + 48];
                    }
                    float gi = ga0 + b0;
                    float gf = ga1 + b1;
                    float gg = ga2 + b2;
                    float go = ga3 + b3;
                    size_t off = (size_t)rowg * a.HH + ub;
                    float cn = sigf(gi) * tanh_f(gg);
                    if (!a.init) cn = fmaf(sigf(gf), (float)a.cb[off], cn);
                    if (!a.fin) a.cb[off] = (f16)cn;   // final step: c is dead
                    a.hb[off] = (f16)(sigf(go) * tanh_f(cn));
                }
            }
    } else {
#pragma unroll
        for (int i = 0; i < 4; ++i)
#pragma unroll
            for (int j = 0; j < 4; ++j) {
                int col = n0 + wn + j * 16 + lr;
#pragma unroll
                for (int r = 0; r < 4; ++r) {
                    int rowg = m0 + wm + i * 16 + kg * 4 + r;
                    if (rowg < a.M) {
                        float xv = (float)a.xff[(size_t)(rowg >> 2) * H + col];
                        float cv = a.cch[(size_t)rowg * H + col];
                        a.fcm[(size_t)rowg * H + col] =
                            (f16)(cv * sigf(xv + acc[i][j][r]));
                    }
                }
            }
    }
}

// ================= 128x128 tile, 256 thr (pair: u | f) =====================
template<int EPI>
__global__ __launch_bounds__(256) void gemm_pair(GArg u, GArg f, int split)
{
    __shared__ f16 As[2][128 * 32];
    __shared__ f16 Bs[2][128 * 32];
    const int tid = threadIdx.x;

    const int gX = gridDim.x, gY = gridDim.y;
    const int orig = blockIdx.y * gX + blockIdx.x;
    const int gXf = gX - split;
    const int nwgU = split * gY, nwgF = gXf * gY;

    int bx, by, isU;
    if (((nwgU | nwgF) & 7) == 0) {
        int cu = nwgU >> 3, cf = nwgF >> 3;
        int xcd = orig & 7, rem = orig >> 3;
        if (rem < cu) { int lid = xcd * cu + rem;        isU = 1; by = lid / split; bx = lid % split; }
        else          { int lid = xcd * cf + (rem - cu); isU = 0; by = lid / gXf;  bx = lid % gXf; }
    } else {
        const int nwg = gX * gY;
        const int q = nwg >> 3, r = nwg & 7;
        const int xcd = orig & 7, rem = orig >> 3;
        const int wgid = (xcd < r ? xcd * (q + 1) : r * (q + 1) + (xcd - r) * q) + rem;
        int bx0 = wgid % gX; by = wgid / gX;
        isU = (bx0 < split);
        bx = isU ? bx0 : bx0 - split;
    }
    const GArg a = isU ? u : f;        // uniform scalar select

    const int m0 = by * 128, n0 = bx * 128;
    const int wave = tid >> 6, lane = tid & 63;
    const int wm = (wave >> 1) * 64, wn = (wave & 1) * 64;
    const int lr = lane & 15, kg = lane >> 4;
    const int px = kg ^ ((lr >> 1) & 3);

    f32x4 acc[4][4];
#pragma unroll
    for (int i = 0; i < 4; ++i)
#pragma unroll
        for (int j = 0; j < 4; ++j) acc[i][j] = (f32x4){0.f, 0.f, 0.f, 0.f};

    const int nt1 = a.K0 >> 5;
    const int nt = nt1 + (a.K1 >> 5);

    auto stage = [&](int t, int b) {
        const f16* Ap; const f16* Bp; int la, lb, k0;
        if (t < nt1) { Ap = a.A0; Bp = a.B0; la = a.la0; lb = a.lb0; k0 = t * 32; }
        else         { Ap = a.A1; Bp = a.B1; la = a.la1; lb = a.lb1; k0 = (t - nt1) * 32; }
#pragma unroll
        for (int v = 0; v < 2; ++v) {
            int idx = v * 256 + tid;
            int row = idx >> 2, cph = idx & 3;
            int clog = cph ^ ((row >> 1) & 3);
            int ar = m0 + row;
            if (ar >= a.M) ar = a.M - 1;
            gload16(Ap + (size_t)ar * la + k0 + clog * 8, &As[b][idx * 8]);
            gload16(Bp + (size_t)(n0 + row) * lb + k0 + clog * 8, &Bs[b][idx * 8]);
        }
    };

    stage(0, 0);
    for (int t = 0; t < nt; ++t) {
        __syncthreads();
        if (t + 1 < nt) stage(t + 1, (t + 1) & 1);
        const f16* as = As[t & 1];
        const f16* bs = Bs[t & 1];
        f16x8 af[4], bfr[4];
#pragma unroll
        for (int i = 0; i < 4; ++i) {
            af[i]  = *(const f16x8*)&as[(wm + i * 16 + lr) * 32 + px * 8];
            bfr[i] = *(const f16x8*)&bs[(wn + i * 16 + lr) * 32 + px * 8];
        }
#pragma unroll
        for (int i = 0; i < 4; ++i)
#pragma unroll
            for (int j = 0; j < 4; ++j)
                acc[i][j] = __builtin_amdgcn_mfma_f32_16x16x32_f16(af[i], bfr[j], acc[i][j], 0, 0, 0);
    }

    if constexpr (EPI == 0) {
#pragma unroll
        for (int i = 0; i < 4; ++i)
#pragma unroll
            for (int j = 0; j < 4; ++j) {
                int col = n0 + wn + j * 16 + lr;
                float bv = a.bias ? a.bias[col] : 0.f;
#pragma unroll
                for (int r = 0; r < 4; ++r) {
                    int rowg = m0 + wm + i * 16 + kg * 4 + r;
                    if (rowg < a.M) {
                        float v = acc[i][j][r] + bv;
                        if (a.Cf) a.Cf[(size_t)rowg * a.ldc + col] = v;
                        if (a.Ch) a.Ch[(size_t)rowg * a.ldc + col] = (f16)v;
                    }
                }
            }
    } else {
        int ub = (n0 >> 2) + (wave & 1) * 16 + lr;
        int c0 = n0 + wn + lr;
        float b0 = a.bias[c0];
        float b1 = a.bias[c0 + 16];
        float b2 = a.bias[c0 + 32];
        float b3 = a.bias[c0 + 48];
        float v0 = 0.f, v1 = 0.f, v2 = 0.f, v3 = 0.f;
        if (a.gvb) {
            v0 = a.gvb[c0];      v1 = a.gvb[c0 + 16];
            v2 = a.gvb[c0 + 32]; v3 = a.gvb[c0 + 48];
        }
#pragma unroll
        for (int i = 0; i < 4; ++i)
#pragma unroll
            for (int r = 0; r < 4; ++r) {
                int rowg = m0 + wm + i * 16 + kg * 4 + r;
                if (rowg < a.M) {
                    float ga0 = acc[i][0][r] + v0, ga1 = acc[i][1][r] + v1;
                    float ga2 = acc[i][2][r] + v2, ga3 = acc[i][3][r] + v3;
                    size_t gbase = (size_t)rowg * a.N + c0;
                    if (a.gst) {
                        a.gst[gbase]      = (f16)ga0;
                        a.gst[gbase + 16] = (f16)ga1;
                        a.gst[gbase + 32] = (f16)ga2;
                        a.gst[gbase + 48] = (f16)ga3;
                    }
                    if (a.gin) {
                        ga0 += (float)a.gin[gbase];
                        ga1 += (float)a.gin[gbase + 16];
                        ga2 += (float)a.gin[gbase + 32];
                        ga3 += (float)a.gin[gbase + 48];
                    }
                    float gi = ga0 + b0;
                    float gf = ga1 + b1;
                    float gg = ga2 + b2;
                    float go = ga3 + b3;
                    size_t off = (size_t)rowg * a.HH + ub;
                    float cn = sigf(gi) * tanh_f(gg);
                    if (!a.init) cn = fmaf(sigf(gf), (float)a.cb[off], cn);
                    if (!a.fin) a.cb[off] = (f16)cn;   // final step: c is dead
                    a.hb[off] = (f16)(sigf(go) * tanh_f(cn));
                }
            }
    }
}

// ================= 128x256 tile, 512 thr (single) ==========================
template<int EPI>
__global__ __launch_bounds__(512) void gemm_big(GArg a)
{
    __shared__ f16 As[2][128 * 32];
    __shared__ f16 Bs[2][256 * 32];
    const int tid = threadIdx.x;

    const int gX = gridDim.x;
    const int nwg = gX * gridDim.y;
    const int orig = blockIdx.y * gX + blockIdx.x;
    const int q = nwg >> 3, r = nwg & 7;
    const int xcd = orig & 7, rem = orig >> 3;
    const int wgid = (xcd < r ? xcd * (q + 1) : r * (q + 1) + (xcd - r) * q) + rem;
    const int bx = wgid % gX, by = wgid / gX;

    const int m0 = by * 128, n0 = bx * 256;
    const int wave = tid >> 6, lane = tid & 63;
    const int wm = (wave >> 2) * 64, wn = (wave & 3) * 64;
    const int lr = lane & 15, kg = lane >> 4;
    const int px = kg ^ ((lr >> 1) & 3);

    f32x4 acc[4][4];
#pragma unroll
    for (int i = 0; i < 4; ++i)
#pragma unroll
        for (int j = 0; j < 4; ++j) acc[i][j] = (f32x4){0.f, 0.f, 0.f, 0.f};

    const int nt1 = a.K0 >> 5;
    const int nt = nt1 + (a.K1 >> 5);

    auto stage = [&](int t, int b) {
        const f16* Ap; const f16* Bp; int la, lb, k0;
        if (t < nt1) { Ap = a.A0; Bp = a.B0; la = a.la0; lb = a.lb0; k0 = t * 32; }
        else         { Ap = a.A1; Bp = a.B1; la = a.la1; lb = a.lb1; k0 = (t - nt1) * 32; }
        {
            int idx = tid;
            int row = idx >> 2, cph = idx & 3;
            int clog = cph ^ ((row >> 1) & 3);
            int ar = m0 + row;
            if (ar >= a.M) ar = a.M - 1;
            gload16(Ap + (size_t)ar * la + k0 + clog * 8, &As[b][idx * 8]);
        }
#pragma unroll
        for (int v = 0; v < 2; ++v) {
            int idx = v * 512 + tid;
            int row = idx >> 2, cph = idx & 3;
            int clog = cph ^ ((row >> 1) & 3);
            gload16(Bp + (size_t)(n0 + row) * lb + k0 + clog * 8, &Bs[b][idx * 8]);
        }
    };

    stage(0, 0);
    for (int t = 0; t < nt; ++t) {
        __syncthreads();
        if (t + 1 < nt) stage(t + 1, (t + 1) & 1);
        const f16* as = As[t & 1];
        const f16* bs = Bs[t & 1];
        f16x8 af[4], bfr[4];
#pragma unroll
        for (int i = 0; i < 4; ++i) {
            af[i]  = *(const f16x8*)&as[(wm + i * 16 + lr) * 32 + px * 8];
            bfr[i] = *(const f16x8*)&bs[(wn + i * 16 + lr) * 32 + px * 8];
        }
#pragma unroll
        for (int i = 0; i < 4; ++i)
#pragma unroll
            for (int j = 0; j < 4; ++j)
                acc[i][j] = __builtin_amdgcn_mfma_f32_16x16x32_f16(af[i], bfr[j], acc[i][j], 0, 0, 0);
    }

    if constexpr (EPI == 0) {
#pragma unroll
        for (int i = 0; i < 4; ++i)
#pragma unroll
            for (int j = 0; j < 4; ++j) {
                int col = n0 + wn + j * 16 + lr;
                float bv = a.bias ? a.bias[col] : 0.f;
#pragma unroll
                for (int r = 0; r < 4; ++r) {
                    int rowg = m0 + wm + i * 16 + kg * 4 + r;
                    if (rowg < a.M) {
                        float v = acc[i][j][r] + bv;
                        if (a.Cf) a.Cf[(size_t)rowg * a.ldc + col] = v;
                        if (a.Ch) a.Ch[(size_t)rowg * a.ldc + col] = (f16)v;
                    }
                }
            }
    } else if constexpr (EPI == 1) {
        int ub = (n0 >> 2) + (wave & 3) * 16 + lr;
        int c0 = n0 + wn + lr;
        float b0 = a.bias[c0];
        float b1 = a.bias[c0 + 16];
        float b2 = a.bias[c0 + 32];
        float b3 = a.bias[c0 + 48];
        float v0 = 0.f, v1 = 0.f, v2 = 0.f, v3 = 0.f;
        if (a.gvb) {
            v0 = a.gvb[c0];      v1 = a.gvb[c0 + 16];
            v2 = a.gvb[c0 + 32]; v3 = a.gvb[c0 + 48];
        }
#pragma unroll
        for (int i = 0; i < 4; ++i)
#pragma unroll
            for (int r = 0; r < 4; ++r) {
                int rowg = m0 + wm + i * 16 + kg * 4 + r;
                if (rowg < a.M) {
                    float ga0 = acc[i][0][r] + v0, ga1 = acc[i][1][r] + v1;
                    float ga2 = acc[i][2][r] + v2, ga3 = acc[i][3][r] + v3;
                    size_t gbase = (size_t)rowg * a.N + c0;
                    if (a.gst) {
                        a.gst[gbase]      = (f16)ga0;
                        a.gst[gbase + 16] = (f16)ga1;
                        a.gst[gbase + 32] = (f16)ga2;
                        a.gst[gbase + 48] = (f16)ga3;
                    }
                    if (a.gin) {
                        ga0 += (float)a.gin[gbase];
                        ga1 += (float)a.gin[gbase + 16];
                        ga2 += (float)a.gin[gbase + 32];
                        ga3 += (float)a.gin[gbase + 48];
                    }
                    float gi = ga0 + b0;
                    float gf = ga1 + b1;
                    float gg = ga2 + b2;
                    float go = ga3 + b3;
                    size_t off = (size_t)rowg * a.HH + ub;
                    float cn = sigf(gi) * tanh_f(gg);
                    if (!a.init) cn = fmaf(sigf(gf), (float)a.cb[off], cn);
                    if (!a.fin) a.cb[off] = (f16)cn;   // final step: c is dead
                    a.hb[off] = (f16)(sigf(go) * tanh_f(cn));
                }
            }
    } else {
#pragma unroll
        for (int i = 0; i < 4; ++i)
#pragma unroll
            for (int j = 0; j < 4; ++j) {
                int col = n0 + wn + j * 16 + lr;
#pragma unroll
                for (int r = 0; r < 4; ++r) {
                    int rowg = m0 + wm + i * 16 + kg * 4 + r;
                    if (rowg < a.M) {
                        float xv = (float)a.xff[(size_t)(rowg >> 2) * H + col];
                        float cv = a.cch[(size_t)rowg * H + col];
                        a.fcm[(size_t)rowg * H + col] =
                            (f16)(cv * sigf(xv + acc[i][j][r]));
                    }
                }
            }
    }
}

// ================= 128x256 tile, 512 thr (pair: u | f) =====================
template<int EPI>
__global__ __launch_bounds__(512) void gemm_pair_big(GArg u, GArg f, int split)
{
    __shared__ f16 As[2][128 * 32];
    __shared__ f16 Bs[2][256 * 32];
    const int tid = threadIdx.x;

    const int gX = gridDim.x, gY = gridDim.y;
    const int orig = blockIdx.y * gX + blockIdx.x;
    const int gXf = gX - split;
    const int nwgU = split * gY, nwgF = gXf * gY;

    int bx, by, isU;
    if (((nwgU | nwgF) & 7) == 0) {
        int cu = nwgU >> 3, cf = nwgF >> 3;
        int xcd = orig & 7, rem = orig >> 3;
        if (rem < cu) { int lid = xcd * cu + rem;        isU = 1; by = lid / split; bx = lid % split; }
        else          { int lid = xcd * cf + (rem - cu); isU = 0; by = lid / gXf;  bx = lid % gXf; }
    } else {
        const int nwg = gX * gY;
        const int q = nwg >> 3, r = nwg & 7;
        const int xcd = orig & 7, rem = orig >> 3;
        const int wgid = (xcd < r ? xcd * (q + 1) : r * (q + 1) + (xcd - r) * q) + rem;
        int bx0 = wgid % gX; by = wgid / gX;
        isU = (bx0 < split);
        bx = isU ? bx0 : bx0 - split;
    }
    const GArg a = isU ? u : f;        // uniform scalar select

    const int m0 = by * 128, n0 = bx * 256;
    const int wave = tid >> 6, lane = tid & 63;
    const int wm = (wave >> 2) * 64, wn = (wave & 3) * 64;
    const int lr = lane & 15, kg = lane >> 4;
    const int px = kg ^ ((lr >> 1) & 3);

    f32x4 acc[4][4];
#pragma unroll
    for (int i = 0; i < 4; ++i)
#pragma unroll
        for (int j = 0; j < 4; ++j) acc[i][j] = (f32x4){0.f, 0.f, 0.f, 0.f};

    const int nt1 = a.K0 >> 5;
    const int nt = nt1 + (a.K1 >> 5);

    auto stage = [&](int t, int b) {
        const f16* Ap; const f16* Bp; int la, lb, k0;
        if (t < nt1) { Ap = a.A0; Bp = a.B0; la = a.la0; lb = a.lb0; k0 = t * 32; }
        else         { Ap = a.A1; Bp = a.B1; la = a.la1; lb = a.lb1; k0 = (t - nt1) * 32; }
        {
            int idx = tid;
            int row = idx >> 2, cph = idx & 3;
            int clog = cph ^ ((row >> 1) & 3);
            int ar = m0 + row;
            if (ar >= a.M) ar = a.M - 1;
            gload16(Ap + (size_t)ar * la + k0 + clog * 8, &As[b][idx * 8]);
        }
#pragma unroll
        for (int v = 0; v < 2; ++v) {
            int idx = v * 512 + tid;
            int row = idx >> 2, cph = idx & 3;
            int clog = cph ^ ((row >> 1) & 3);
            gload16(Bp + (size_t)(n0 + row) * lb + k0 + clog * 8, &Bs[b][idx * 8]);
        }
    };

    stage(0, 0);
    for (int t = 0; t < nt; ++t) {
        __syncthreads();
        if (t + 1 < nt) stage(t + 1, (t + 1) & 1);
        const f16* as = As[t & 1];
        const f16* bs = Bs[t & 1];
        f16x8 af[4], bfr[4];
#pragma unroll
        for (int i = 0; i < 4; ++i) {
            af[i]  = *(const f16x8*)&as[(wm + i * 16 + lr) * 32 + px * 8];
            bfr[i] = *(const f16x8*)&bs[(wn + i * 16 + lr) * 32 + px * 8];
        }
#pragma unroll
        for (int i = 0; i < 4; ++i)
#pragma unroll
            for (int j = 0; j < 4; ++j)
                acc[i][j] = __builtin_amdgcn_mfma_f32_16x16x32_f16(af[i], bfr[j], acc[i][j], 0, 0, 0);
    }

    if constexpr (EPI == 0) {
#pragma unroll
        for (int i = 0; i < 4; ++i)
#pragma unroll
            for (int j = 0; j < 4; ++j) {
                int col = n0 + wn + j * 16 + lr;
                float bv = a.bias ? a.bias[col] : 0.f;
#pragma unroll
                for (int r = 0; r < 4; ++r) {
                    int rowg = m0 + wm + i * 16 + kg * 4 + r;
                    if (rowg < a.M) {
                        float v = acc[i][j][r] + bv;
                        if (a.Cf) a.Cf[(size_t)rowg * a.ldc + col] = v;
                        if (a.Ch) a.Ch[(size_t)rowg * a.ldc + col] = (f16)v;
                    }
                }
            }
    } else {
        int ub = (n0 >> 2) + (wave & 3) * 16 + lr;
        int c0 = n0 + wn + lr;
        float b0 = a.bias[c0];
        float b1 = a.bias[c0 + 16];
        float b2 = a.bias[c0 + 32];
        float b3 = a.bias[c0 + 48];
        float v0 = 0.f, v1 = 0.f, v2 = 0.f, v3 = 0.f;
        if (a.gvb) {
            v0 = a.gvb[c0];      v1 = a.gvb[c0 + 16];
            v2 = a.gvb[c0 + 32]; v3 = a.gvb[c0 + 48];
        }
#pragma unroll
        for (int i = 0; i < 4; ++i)
#pragma unroll
            for (int r = 0; r < 4; ++r) {
                int rowg = m0 + wm + i * 16 + kg * 4 + r;
                if (rowg < a.M) {
                    float ga0 = acc[i][0][r] + v0, ga1 = acc[i][1][r] + v1;
                    float ga2 = acc[i][2][r] + v2, ga3 = acc[i][3][r] + v3;
                    size_t gbase = (size_t)rowg * a.N + c0;
                    if (a.gst) {
                        a.gst[gbase]      = (f16)ga0;
                        a.gst[gbase + 16] = (f16)ga1;
                        a.gst[gbase + 32] = (f16)ga2;
                        a.gst[gbase + 48] = (f16)ga3;
                    }
                    if (a.gin) {
                        ga0 += (float)a.gin[gbase];
                        ga1 += (float)a.gin[gbase + 16];
                        ga2 += (float)a.gin[gbase + 32];
                        ga3 += (float)a.gin[gbase + 48];
                    }
                    float gi = ga0 + b0;
                    float gf = ga1 + b1;
                    float gg = ga2 + b2;
                    float go = ga3 + b3;
                    size_t off = (size_t)rowg * a.HH + ub;
                    float cn = sigf(gi) * tanh_f(gg);
                    if (!a.init) cn = fmaf(sigf(gf), (float)a.cb[off], cn);
                    if (!a.fin) a.cb[off] = (f16)cn;   // final step: c is dead
                    a.hb[off] = (f16)(sigf(go) * tanh_f(cn));
                }
            }
    }
}

// ---------------- f32 tiled NT GEMM (prep only: folded weights) ----------------
__global__ __launch_bounds__(256) void gemm_nt_f32(
    const float* __restrict__ A, int lda,
    const float* __restrict__ B, int ldb,
    float* __restrict__ C, int ldc, int M, int N, int K)
{
    __shared__ float As[16][128];
    __shared__ float Bs[16][128];
    const int m0 = blockIdx.y * 128, n0 = blockIdx.x * 128;
    const int tid = threadIdx.x;
    const int tx = tid & 15, ty = tid >> 4;
    float acc[8][8];
#pragma unroll
    for (int i = 0; i < 8; ++i)
#pragma unroll
        for (int j = 0; j < 8; ++j) acc[i][j] = 0.0f;
    for (int k0 = 0; k0 < K; k0 += 16) {
#pragma unroll
        for (int v = 0; v < 2; ++v) {
            int idx = tid + v * 256;
            int row = idx >> 2, c4 = idx & 3;
            float4 av = make_float4(0, 0, 0, 0);
            int gm = m0 + row;
            if (gm < M) av = *(const float4*)&A[(size_t)gm * lda + k0 + c4 * 4];
            As[c4 * 4 + 0][row] = av.x; As[c4 * 4 + 1][row] = av.y;
            As[c4 * 4 + 2][row] = av.z; As[c4 * 4 + 3][row] = av.w;
            float4 bv = make_float4(0, 0, 0, 0);
            int gn = n0 + row;
            if (gn < N) bv = *(const float4*)&B[(size_t)gn * ldb + k0 + c4 * 4];
            Bs[c4 * 4 + 0][row] = bv.x; Bs[c4 * 4 + 1][row] = bv.y;
            Bs[c4 * 4 + 2][row] = bv.z; Bs[c4 * 4 + 3][row] = bv.w;
        }
        __syncthreads();
#pragma unroll
        for (int kk = 0; kk < 16; ++kk) {
            float4 a0 = *(const float4*)&As[kk][ty * 8];
            float4 a1 = *(const float4*)&As[kk][ty * 8 + 4];
            float4 b0 = *(const float4*)&Bs[kk][tx * 8];
            float4 b1 = *(const float4*)&Bs[kk][tx * 8 + 4];
            float av[8] = { a0.x,a0.y,a0.z,a0.w,a1.x,a1.y,a1.z,a1.w };
            float bv[8] = { b0.x,b0.y,b0.z,b0.w,b1.x,b1.y,b1.z,b1.w };
#pragma unroll
            for (int i = 0; i < 8; ++i)
#pragma unroll
                for (int j = 0; j < 8; ++j)
                    acc[i][j] = fmaf(av[i], bv[j], acc[i][j]);
        }
        __syncthreads();
    }
#pragma unroll
    for (int i = 0; i < 8; ++i) {
        int gm = m0 + ty * 8 + i;
        if (gm >= M) break;
#pragma unroll
        for (int j = 0; j < 8; ++j) {
            int gn = n0 + tx * 8 + j;
            if (gn < N) C[(size_t)gm * ldc + gn] = acc[i][j];
        }
    }
}

// ---------------- elementwise / prep kernels ----------------

// leaves: iou f16 [count,768] -> h f16, c f32 (pointers pre-offset)
__global__ __launch_bounds__(256) void leaf_apply(
    const f16* __restrict__ iou, f16* __restrict__ hh, float* __restrict__ c,
    int count)
{
    int idx = blockIdx.x * 256 + threadIdx.x;
    int tot = count * (H / 4);
    if (idx >= tot) return;
    int row = idx >> 6;
    int c4 = (idx & 63) * 4;
    const f16* r = iou + (size_t)row * H3;
    f16x4 vi = *(const f16x4*)&r[c4];
    f16x4 vo = *(const f16x4*)&r[H + c4];
    f16x4 vu = *(const f16x4*)&r[2 * H + c4];
    size_t off = (size_t)row * H + c4;
    float cc[4]; f16x4 hq;
#pragma unroll
    for (int j = 0; j < 4; ++j) {
        cc[j] = sigf((float)vi[j]) * tanh_f((float)vu[j]);
        hq[j] = (f16)(sigf((float)vo[j]) * tanh_f(cc[j]));
    }
    *(float4*)&c[off] = make_float4(cc[0], cc[1], cc[2], cc[3]);
    *(f16x4*)&hh[off] = hq;
}

// internal apply: all f16 inputs; h f16 + c f32 out (pointers pre-offset)
__global__ __launch_bounds__(256) void node_apply(
    const f16* __restrict__ xiou, const f16* __restrict__ h_uh,
    const f16* __restrict__ hfc, f16* __restrict__ hh, float* __restrict__ c,
    int Cn)
{
    int idx = blockIdx.x * 256 + threadIdx.x;
    int tot = Cn * (H / 4);
    if (idx >= tot) return;
    int row = idx >> 6;
    int c4 = (idx & 63) * 4;
    const f16* xr = xiou + (size_t)row * H3;
    const f16* ur = h_uh + (size_t)row * H3;
    f16x4 xi = *(const f16x4*)&xr[c4];
    f16x4 xo = *(const f16x4*)&xr[H + c4];
    f16x4 xu = *(const f16x4*)&xr[2 * H + c4];
    f16x4 ui = *(const f16x4*)&ur[c4];
    f16x4 uo = *(const f16x4*)&ur[H + c4];
    f16x4 uu = *(const f16x4*)&ur[2 * H + c4];
    f16x4 fv = *(const f16x4*)&hfc[(size_t)row * H + c4];
    size_t off = (size_t)row * H + c4;
    float cc[4]; f16x4 hq;
#pragma unroll
    for (int j = 0; j < 4; ++j) {
        float iv = (float)xi[j] + (float)ui[j];
        float ov = (float)xo[j] + (float)uo[j];
        float uv = (float)xu[j] + (float)uu[j];
        float cv = sigf(iv) * tanh_f(uv) + (float)fv[j];
        cc[j] = cv;
        hq[j] = (f16)(sigf(ov) * tanh_f(cv));
    }
    *(float4*)&c[off] = make_float4(cc[0], cc[1], cc[2], cc[3]);
    *(f16x4*)&hh[off] = hq;
}

__global__ __launch_bounds__(256) void bias_sum(
    const float* __restrict__ a, const float* __restrict__ b, float* __restrict__ o, int n)
{
    int i = blockIdx.x * 256 + threadIdx.x;
    if (i < n) o[i] = a[i] + b[i];
}

// y[m] = dot(A[m,:], x) — folded-bias vector (prep only)
__global__ __launch_bounds__(256) void matvec_f32(
    const float* __restrict__ A, const float* __restrict__ x,
    float* __restrict__ y, int M, int K)
{
    int m = blockIdx.x * 256 + threadIdx.x;
    if (m >= M) return;
    const float* r = A + (size_t)m * K;
    float s = 0.f;
    for (int k = 0; k < K; k += 4) {
        float4 a = *(const float4*)&r[k];
        float4 b = *(const float4*)&x[k];
        s += a.x * b.x + a.y * b.y + a.z * b.z + a.w * b.w;
    }
    y[m] = s;
}

__global__ __launch_bounds__(256) void cvt_f16(
    const float* __restrict__ in, f16* __restrict__ out, int n)
{
    int idx = blockIdx.x * 256 + threadIdx.x;
    if (idx * 4 >= n) return;
    float4 v = *(const float4*)&in[idx * 4];
    f16x4 o; o[0] = (f16)v.x; o[1] = (f16)v.y; o[2] = (f16)v.z; o[3] = (f16)v.w;
    *(f16x4*)&out[idx * 4] = o;
}

__global__ __launch_bounds__(256) void permute_cvt(
    const float* __restrict__ src, f16* __restrict__ dst, int HH, int K, int tot4)
{
    int idx = blockIdx.x * 256 + threadIdx.x;
    if (idx >= tot4) return;
    int kq = K >> 2;
    int m = idx / kq;
    int k4 = (idx - m * kq) * 4;
    int gate = (m >> 4) & 3;
    int unit = (m >> 7) * 32 + ((m >> 6) & 1) * 16 + (m & 15);
    float4 v = *(const float4*)&src[(size_t)(gate * HH + unit) * K + k4];
    f16x4 o; o[0] = (f16)v.x; o[1] = (f16)v.y; o[2] = (f16)v.z; o[3] = (f16)v.w;
    *(f16x4*)&dst[(size_t)m * K + k4] = o;
}

__global__ __launch_bounds__(256) void permute_bias(
    const float* __restrict__ src, float* __restrict__ dst, int HH, int n)
{
    int m = blockIdx.x * 256 + threadIdx.x;
    if (m >= n) return;
    int gate = (m >> 4) & 3;
    int unit = (m >> 7) * 32 + ((m >> 6) & 1) * 16 + (m & 15);
    dst[m] = src[gate * HH + unit];
}

__global__ __launch_bounds__(256) void transpose_f32(
    const float* __restrict__ in, float* __restrict__ out)
{
    int idx = blockIdx.x * 256 + threadIdx.x;
    if (idx >= H3 * E) return;
    int r = idx >> 8, c = idx & 255;
    out[(size_t)c * H3 + r] = in[idx];
}

__global__ __launch_bounds__(256) void ln_tanh(
    float* __restrict__ y, const float* __restrict__ g, const float* __restrict__ b,
    int Nrows)
{
    int wave = threadIdx.x >> 6;
    int lane = threadIdx.x & 63;
    int row = blockIdx.x * 4 + wave;
    if (row >= Nrows) return;
    float* yr = y + (size_t)row * DEC;
    float4 v0 = *(const float4*)&yr[lane * 8];
    float4 v1 = *(const float4*)&yr[lane * 8 + 4];
    float s = v0.x + v0.y + v0.z + v0.w + v1.x + v1.y + v1.z + v1.w;
    float s2 = v0.x * v0.x + v0.y * v0.y + v0.z * v0.z + v0.w * v0.w +
               v1.x * v1.x + v1.y * v1.y + v1.z * v1.z + v1.w * v1.w;
#pragma unroll
    for (int off = 32; off; off >>= 1) {
        s += __shfl_xor(s, off);
        s2 += __shfl_xor(s2, off);
    }
    float m = s * (1.0f / DEC);
    float var = s2 * (1.0f / DEC) - m * m;
    float rstd = rsqrtf(var + 1e-5f);
    float vals[8] = { v0.x,v0.y,v0.z,v0.w,v1.x,v1.y,v1.z,v1.w };
    float o[8];
#pragma unroll
    for (int j = 0; j < 8; ++j) {
        int colj = lane * 8 + j;
        o[j] = tanh_f((vals[j] - m) * rstd * g[colj] + b[colj]);
    }
    *(float4*)&yr[lane * 8] = make_float4(o[0], o[1], o[2], o[3]);
    *(float4*)&yr[lane * 8 + 4] = make_float4(o[4], o[5], o[6], o[7]);
}

// ---------------- host ----------------
extern "C" void kernel_launch(void* const* d_in, const int* in_sizes, int n_in,
                              void* d_out, int out_size, void* d_ws, size_t ws_size,
                              hipStream_t stream)
{
    (void)in_sizes; (void)n_in; (void)out_size;
    const float* embed   = (const float*)d_in[0];
    const float* W_iou_w = (const float*)d_in[1];
    const float* W_iou_b = (const float*)d_in[2];
    const float* U_iou_w = (const float*)d_in[3];
    const float* W_f_w   = (const float*)d_in[4];
    const float* W_f_b   = (const float*)d_in[5];
    const float* U_f_w   = (const float*)d_in[6];
    const float* uh_wih  = (const float*)d_in[7];
    const float* uh_whh  = (const float*)d_in[8];
    const float* uh_bih  = (const float*)d_in[9];
    const float* uh_bhh  = (const float*)d_in[10];
    const float* fc_wih  = (const float*)d_in[11];
    const float* fc_whh  = (const float*)d_in[12];
    const float* fc_bih  = (const float*)d_in[13];
    const float* fc_bhh  = (const float*)d_in[14];
    const float* out_w   = (const float*)d_in[15];
    const float* out_b   = (const float*)d_in[16];
    const float* ln_g    = (const float*)d_in[17];
    const float* ln_b    = (const float*)d_in[18];

    float* out  = (float*)d_out;
    float* cbuf = out;

    float* ws = (float*)d_ws;
    size_t o = 0;
    f16* embed_h = (f16*)(ws + o); o += (size_t)NNODES * E / 2;
    f16* hbuf_h  = (f16*)(ws + o); o += (size_t)NNODES * H / 2;
    f16* wiou_h  = (f16*)(ws + o); o += (size_t)H3 * E / 2;
    f16* wf_h    = (f16*)(ws + o); o += (size_t)H * E / 2;
    f16* uf_h    = (f16*)(ws + o); o += (size_t)H * H / 2;
    f16* wih_p   = (f16*)(ws + o); o += (size_t)GUH * H3 / 2;
    f16* whh_p   = (f16*)(ws + o); o += (size_t)GUH * H3 / 2;
    f16* fih_p   = (f16*)(ws + o); o += (size_t)GFC * H / 2;
    f16* fhh_p   = (f16*)(ws + o); o += (size_t)GFC * H / 2;
    f16* ow_h    = (f16*)(ws + o); o += (size_t)DEC * H / 2;
    f16* fold_p  = (f16*)(ws + o); o += (size_t)GUH * E / 2;
    f16* fold2_p = (f16*)(ws + o); o += (size_t)GUH * E / 2;   // R26: Wih·W_iou folded
    float* fold_f = ws + o; o += (size_t)GUH * E;
    float* Ut     = ws + o; o += (size_t)E * H3;
    float* bsu    = ws + o; o += GUH;
    float* bsf    = ws + o; o += GFC;
    float* pbu    = ws + o; o += GUH;
    float* pbf    = ws + o; o += GFC;
    float* gvbr   = ws + o; o += GUH;                          // R26: Wih·b_iou raw
    float* gvbu   = ws + o; o += GUH;                          // R26: permuted

    // per-chunk f32 words/row:
    // xiou_h 384 + xf_h 128 + gbuf 3072 + hfc0 128 + hfc1 128 + cfc 128
    // + huh0 384 + huh1 384 + c_uh 384 + fcm_h 512 = 5632
    size_t avail = ws_size / 4;
    long long room = (long long)avail - (long long)o - 8192;
    long long Cl = room / 5632;
    int C;
    if (Cl >= 16384) C = 16384;
    else if (Cl <= 256) C = 256;
    else C = (int)((Cl / 256) * 256);

    f16*   xiou_h = (f16*)(ws + o); o += (size_t)C * H3 / 2;
    f16*   xf_h   = (f16*)(ws + o); o += (size_t)C * H / 2;
    float* gbuf   = ws + o; o += (size_t)4 * C * H3;   // leaf iou f16 region; later tok store
    f16*   hfc0   = (f16*)(ws + o); o += (size_t)C * H / 2;
    f16*   hfc1   = (f16*)(ws + o); o += (size_t)C * H / 2;
    f16*   cfc    = (f16*)(ws + o); o += (size_t)C * H / 2;   // f16 level-local c
    f16*   huh0   = (f16*)(ws + o); o += (size_t)C * H3 / 2;
    f16*   huh1   = (f16*)(ws + o); o += (size_t)C * H3 / 2;
    f16*   c_uh   = (f16*)(ws + o); o += (size_t)C * H3 / 2;  // f16 level-local c
    f16*   fcm_h  = (f16*)(ws + o); o += (size_t)4 * C * H / 2;

    f16* huh[2] = { huh0, huh1 };
    f16* hfc[2] = { hfc0, hfc1 };

    // leaf iou (f16) and tok_ih stores (f16) carved from gbuf:
    f16* leaf_h = (f16*)gbuf;                              // [4C x 768] f16
    f16* toku   = (f16*)gbuf;                              // [C x 3072] f16 (after leaves)
    f16* tokf   = (f16*)(gbuf + (size_t)C * 1536);         // [C x 1024] f16

    auto L0 = [&](const GArg& a) {
        if (a.M >= 8192)
            gemm_big<0><<<dim3(a.N / 256, (a.M + 127) / 128), 512, 0, stream>>>(a);
        else
            gemm_one<0><<<dim3(a.N / 128, (a.M + 127) / 128), 256, 0, stream>>>(a);
    };
    auto P0 = [&](const GArg& u, const GArg& f) {
        if (u.M >= 8192)
            gemm_pair_big<0><<<dim3(u.N / 256 + f.N / 256, (u.M + 127) / 128), 512, 0, stream>>>(u, f, u.N / 256);
        else
            gemm_pair<0><<<dim3(u.N / 128 + f.N / 128, (u.M + 127) / 128), 256, 0, stream>>>(u, f, u.N / 128);
    };
    auto P1 = [&](const GArg& u, const GArg& f) {
        if (u.M >= 8192)
            gemm_pair_big<1><<<dim3(u.N / 256 + f.N / 256, (u.M + 127) / 128), 512, 0, stream>>>(u, f, u.N / 256);
        else
            gemm_pair<1><<<dim3(u.N / 128 + f.N / 128, (u.M + 127) / 128), 256, 0, stream>>>(u, f, u.N / 128);
    };

    // ---- prep ----
    auto CVT = [&](const float* s, f16* dv, int n) {
        cvt_f16<<<(n / 4 + 255) / 256, 256, 0, stream>>>(s, dv, n);
    };
    CVT(embed, embed_h, NNODES * E);
    CVT(W_iou_w, wiou_h, H3 * E);
    CVT(W_f_w, wf_h, H * E);
    CVT(U_f_w, uf_h, H * H);
    CVT(out_w, ow_h, DEC * H);
    permute_cvt<<<(GUH * H3 / 4 + 255) / 256, 256, 0, stream>>>(uh_wih, wih_p, H3, H3, GUH * H3 / 4);
    permute_cvt<<<(GUH * H3 / 4 + 255) / 256, 256, 0, stream>>>(uh_whh, whh_p, H3, H3, GUH * H3 / 4);
    permute_cvt<<<(GFC * H / 4 + 255) / 256, 256, 0, stream>>>(fc_wih, fih_p, H, H, GFC * H / 4);
    permute_cvt<<<(GFC * H / 4 + 255) / 256, 256, 0, stream>>>(fc_whh, fhh_p, H, H, GFC * H / 4);
    bias_sum<<<(GUH + 255) / 256, 256, 0, stream>>>(uh_bih, uh_bhh, bsu, GUH);
    bias_sum<<<(GFC + 255) / 256, 256, 0, stream>>>(fc_bih, fc_bhh, bsf, GFC);
    permute_bias<<<(GUH + 255) / 256, 256, 0, stream>>>(bsu, pbu, H3, GUH);
    permute_bias<<<(GFC + 255) / 256, 256, 0, stream>>>(bsf, pbf, H, GFC);
    // fold 1: Wih @ U_iou (message-path A0 for t=1..4)
    transpose_f32<<<(H3 * E + 255) / 256, 256, 0, stream>>>(U_iou_w, Ut);
    {
        dim3 grid(E / 128, GUH / 128);
        gemm_nt_f32<<<grid, 256, 0, stream>>>(uh_wih, H3, Ut, H3, fold_f, E, GUH, E, H3);
        permute_cvt<<<(GUH * E / 4 + 255) / 256, 256, 0, stream>>>(fold_f, fold_p, H3, E, GUH * E / 4);
    }
    // fold 2 (R26): Wih @ W_iou — t=0's tok GEMM becomes K=E. Ut/fold_f reused (dead).
    transpose_f32<<<(H3 * E + 255) / 256, 256, 0, stream>>>(W_iou_w, Ut);
    {
        dim3 grid(E / 128, GUH / 128);
        gemm_nt_f32<<<grid, 256, 0, stream>>>(uh_wih, H3, Ut, H3, fold_f, E, GUH, E, H3);
        permute_cvt<<<(GUH * E / 4 + 255) / 256, 256, 0, stream>>>(fold_f, fold2_p, H3, E, GUH * E / 4);
    }
    // gvb = Wih @ b_iou (the constant bias term the fold drops), permuted
    matvec_f32<<<(GUH + 255) / 256, 256, 0, stream>>>(uh_wih, W_iou_b, gvbr, GUH, H3);
    permute_bias<<<(GUH + 255) / 256, 256, 0, stream>>>(gvbr, gvbu, H3, GUH);

    // ---- leaves (iou in f16) ----
    for (int ls = 0; ls < NLEAF; ls += 4 * C) {
        int Ln = NLEAF - ls < 4 * C ? NLEAF - ls : 4 * C;
        GArg a{};
        a.A0 = embed_h + (size_t)(LEAF0 + ls) * E; a.la0 = E;
        a.B0 = wiou_h; a.lb0 = E; a.K0 = E;
        a.bias = W_iou_b; a.Ch = leaf_h; a.ldc = H3; a.M = Ln; a.N = H3;
        L0(a);
        leaf_apply<<<(Ln * 64 + 255) / 256, 256, 0, stream>>>(
            leaf_h, hbuf_h + (size_t)(LEAF0 + ls) * H, cbuf + (size_t)(LEAF0 + ls) * H, Ln);
    }

    // ---- levels, deepest internal -> root ----
    const int counts[8] = { 1, 4, 16, 64, 256, 1024, 4096, 16384 };
    const int offs[8]   = { 0, 1, 5, 21, 85, 341, 1365, 5461 };
    for (int d = 7; d >= 0; --d) {
        int n = counts[d], start = offs[d];
        for (int s = 0; s < n; s += C) {
            int Cn = n - s < C ? n - s : C;
            int sa = start + s;
            int cst = 4 * sa + 1;

            // x projections: iou | f merged (f16 shadows only)
            {
                GArg u{};
                u.A0 = embed_h + (size_t)sa * E; u.la0 = E;
                u.B0 = wiou_h; u.lb0 = E; u.K0 = E;
                u.bias = W_iou_b; u.Ch = xiou_h; u.ldc = H3;
                u.M = Cn; u.N = H3;
                GArg f = u;
                f.B0 = wf_h; f.bias = W_f_b; f.Ch = xf_h; f.ldc = H; f.N = H;
                P0(u, f);
            }
            // fc messages (GEMM + fc_msg fused; x_f read f16)
            {
                GArg a{};
                a.A0 = hbuf_h + (size_t)cst * H; a.la0 = H;
                a.B0 = uf_h; a.lb0 = H; a.K0 = H;
                a.xff = xf_h; a.cch = cbuf + (size_t)cst * H; a.fcm = fcm_h;
                a.M = 4 * Cn; a.N = H;
                if (a.M >= 8192)
                    gemm_big<2><<<dim3(1, (a.M + 127) / 128), 512, 0, stream>>>(a);
                else
                    gemm_one<2><<<dim3(H / 128, (a.M + 127) / 128), 256, 0, stream>>>(a);
            }
            // 6 LSTM steps; uh | fc merged per step, h double-buffered:
            // step t reads h[(t+1)&1], writes h[t&1]. t=0 (u-side) uses the
            // fold2 path: embed@fold2 (K=E) + gvb == x_iou@Wih; stores tok
            // (f16); t=5 adds it back (K halved), skips dead c-write (fin=1).
            for (int t = 0; t <= 5; ++t) {
                int wb = t & 1, rb = (t + 1) & 1;

                GArg u{};
                u.bias = pbu; u.cb = c_uh; u.hb = huh[wb]; u.HH = H3;
                u.M = Cn; u.N = GUH;
                if (t == 0) {
                    u.A0 = embed_h + (size_t)sa * E; u.la0 = E;
                    u.B0 = fold2_p; u.lb0 = E; u.K0 = E;
                    u.init = 1;
                    u.gst = toku;
                    u.gvb = gvbu;
                } else if (t <= 4) {
                    u.A0 = hbuf_h + (size_t)(cst + t - 1) * H; u.la0 = 4 * H;
                    u.B0 = fold_p; u.lb0 = E; u.K0 = E;
                    u.A1 = huh[rb]; u.la1 = H3; u.B1 = whh_p; u.lb1 = H3; u.K1 = H3;
                } else {
                    u.A0 = huh[rb]; u.la0 = H3; u.B0 = whh_p; u.lb0 = H3; u.K0 = H3;
                    u.gin = toku;
                    u.fin = 1;
                }

                GArg f{};
                f.bias = pbf; f.cb = cfc; f.hb = hfc[wb]; f.HH = H;
                f.M = Cn; f.N = GFC;
                if (t == 0) {
                    f.A0 = xf_h; f.la0 = H; f.B0 = fih_p; f.lb0 = H; f.K0 = H;
                    f.init = 1;
                    f.gst = tokf;
                } else if (t <= 4) {
                    f.A0 = fcm_h + (size_t)(t - 1) * H; f.la0 = 4 * H;
                    f.B0 = fih_p; f.lb0 = H; f.K0 = H;
                    f.A1 = hfc[rb]; f.la1 = H; f.B1 = fhh_p; f.lb1 = H; f.K1 = H;
                } else {
                    f.A0 = hfc[rb]; f.la0 = H; f.B0 = fhh_p; f.lb0 = H; f.K0 = H;
                    f.gin = tokf;
                    f.fin = 1;
                }
                P1(u, f);
            }
            // apply node func (f16 inputs; t=5 wrote huh[1]/hfc[1])
            node_apply<<<(Cn * 64 + 255) / 256, 256, 0, stream>>>(
                xiou_h, huh[1], hfc[1],
                hbuf_h + (size_t)sa * H, cbuf + (size_t)sa * H, Cn);
        }
    }

    // ---- output projection (reads only ws; cbuf is dead) + LN/tanh ----
    {
        GArg a{};
        a.A0 = hbuf_h; a.la0 = H; a.B0 = ow_h; a.lb0 = H; a.K0 = H;
        a.bias = out_b; a.Cf = out; a.ldc = DEC; a.M = NNODES; a.N = DEC;
        L0(a);
    }
    ln_tanh<<<(NNODES + 3) / 4, 256, 0, stream>>>(out, ln_g, ln_b, NNODES);
}

// Round 27
// 3023.560 us; speedup vs baseline: 1.0939x; 1.0407x over previous
//
#include <hip/hip_runtime.h>
#include <math.h>
#include <cstddef>

// ---------------- constants ----------------
constexpr int E = 256, H = 256, H3 = 768;
constexpr int GUH = 3072, GFC = 1024, DEC = 512;
constexpr int NNODES = 87381, LEAF0 = 21845, NLEAF = 65536;

using f16 = _Float16;
typedef __attribute__((ext_vector_type(8))) _Float16 f16x8;
typedef __attribute__((ext_vector_type(4))) _Float16 f16x4;
typedef __attribute__((ext_vector_type(4))) float f32x4;
typedef unsigned int u32;
typedef __attribute__((address_space(1))) const u32 gu32;
typedef __attribute__((address_space(3))) u32 lu32;

// fast transcendentals: v_exp_f32 / v_rcp_f32 based, ~1e-6 rel err
static __device__ __forceinline__ float frcp(float x) { return __builtin_amdgcn_rcpf(x); }
static __device__ __forceinline__ float sigf(float x) { return frcp(1.0f + __expf(-x)); }
static __device__ __forceinline__ float tanh_f(float x) {
    float e = __expf(fminf(2.0f * x, 30.0f));   // clamp avoids inf/inf
    return (e - 1.0f) * frcp(e + 1.0f);
}
static __device__ __forceinline__ void gload16(const void* g, void* l) {
    __builtin_amdgcn_global_load_lds((gu32*)g, (lu32*)l, 16, 0, 0);
}

// GArg + EPI semantics:
// out[m,n] = sum_k A0[m,k]B0[n,k] + sum_k A1[m,k]B1[n,k]  (K0/K1 mult of 32)
// EPI 0: +bias -> Cf f32 / Ch f16 (either or both)
// EPI 1: LSTM cell. B rows gate-interleaved: row m <-> gate=(m>>4)&3,
//        unit=(m>>7)*32+((m>>6)&1)*16+(m&15). Fragment j == gate. Writes
//        c (f16, level-local; SKIPPED when fin=1 — final step, c dead),
//        h (f16).
//        gvb: constant per-column add (folded-bias) applied BEFORE gst —
//             so the stored tok equals the true x_iou@Wih^T (fold2 path).
//        gst: store raw acc(+gvb) (f16) at [row*N + permuted col] (t=0);
//        gin: add stored acc back before bias (t=5; same col formula).
//        RACE SAFETY: hb must differ from every A input (h double-buffered).
// EPI 2: fc-message: fcm[r,col] = cch[r,col] * sigmoid(xff[r>>2,col] + acc)
//        (xff is f16)
// A rows clamped to M-1 during staging. LDS bank-conflict swizzle: chunk
// c_phys = c_logical ^ ((row>>1)&3) on source addr and read addr.
// XCD-aware bijective block swizzle (m204); pair kernels use a per-XCD
// BALANCED split (each XCD gets contiguous chunks of BOTH sub-problems)
// when both sub-grid sizes are divisible by 8 (prevents L2 thrash).
// R25 LESSON: 128x128-only routing REGRESSED; 128x256/512thr stays for
// M>=8192. R26 LESSON: a second gemm_nt_f32 fold costs ~60us of prep
// (48 blocks, parallelism-starved) — R27 merges both folds into ONE
// N=512 gemm_nt_f32 call (96 blocks, same wall time as N=256).
// CODEGEN RULE (R7/R15 lesson): kernel bodies stay fully inline with their
// __shared__ decls; never pass LDS pointers through helpers. Pair kernels
// select between two GArg by a uniform scalar copy only.
struct GArg {
    const f16 *A0 = nullptr, *B0 = nullptr, *A1 = nullptr, *B1 = nullptr;
    int la0 = 0, lb0 = 0, K0 = 0, la1 = 0, lb1 = 0, K1 = 0;
    const float* bias = nullptr;
    float* Cf = nullptr; f16* Ch = nullptr; int ldc = 0;              // EPI 0
    f16* cb = nullptr; f16* hb = nullptr;                             // EPI 1
    int HH = 0; int init = 0; int fin = 0;                            // EPI 1
    const float* gvb = nullptr;                                       // EPI 1 folded bias
    f16* gst = nullptr; const f16* gin = nullptr;                    // EPI 1 tok reuse
    const f16* xff = nullptr; const float* cch = nullptr; f16* fcm = nullptr; // EPI 2
    int M = 0, N = 0;
};

// ================= 128x128 tile, 256 thr (single) ==========================
template<int EPI>
__global__ __launch_bounds__(256) void gemm_one(GArg a)
{
    __shared__ f16 As[2][128 * 32];
    __shared__ f16 Bs[2][128 * 32];
    const int tid = threadIdx.x;

    const int gX = gridDim.x;
    const int nwg = gX * gridDim.y;
    const int orig = blockIdx.y * gX + blockIdx.x;
    const int q = nwg >> 3, r = nwg & 7;
    const int xcd = orig & 7, rem = orig >> 3;
    const int wgid = (xcd < r ? xcd * (q + 1) : r * (q + 1) + (xcd - r) * q) + rem;
    const int bx = wgid % gX, by = wgid / gX;

    const int m0 = by * 128, n0 = bx * 128;
    const int wave = tid >> 6, lane = tid & 63;
    const int wm = (wave >> 1) * 64, wn = (wave & 1) * 64;
    const int lr = lane & 15, kg = lane >> 4;
    const int px = kg ^ ((lr >> 1) & 3);

    f32x4 acc[4][4];
#pragma unroll
    for (int i = 0; i < 4; ++i)
#pragma unroll
        for (int j = 0; j < 4; ++j) acc[i][j] = (f32x4){0.f, 0.f, 0.f, 0.f};

    const int nt1 = a.K0 >> 5;
    const int nt = nt1 + (a.K1 >> 5);

    auto stage = [&](int t, int b) {
        const f16* Ap; const f16* Bp; int la, lb, k0;
        if (t < nt1) { Ap = a.A0; Bp = a.B0; la = a.la0; lb = a.lb0; k0 = t * 32; }
        else         { Ap = a.A1; Bp = a.B1; la = a.la1; lb = a.lb1; k0 = (t - nt1) * 32; }
#pragma unroll
        for (int v = 0; v < 2; ++v) {
            int idx = v * 256 + tid;
            int row = idx >> 2, cph = idx & 3;
            int clog = cph ^ ((row >> 1) & 3);
            int ar = m0 + row;
            if (ar >= a.M) ar = a.M - 1;
            gload16(Ap + (size_t)ar * la + k0 + clog * 8, &As[b][idx * 8]);
            gload16(Bp + (size_t)(n0 + row) * lb + k0 + clog * 8, &Bs[b][idx * 8]);
        }
    };

    stage(0, 0);
    for (int t = 0; t < nt; ++t) {
        __syncthreads();
        if (t + 1 < nt) stage(t + 1, (t + 1) & 1);
        const f16* as = As[t & 1];
        const f16* bs = Bs[t & 1];
        f16x8 af[4], bfr[4];
#pragma unroll
        for (int i = 0; i < 4; ++i) {
            af[i]  = *(const f16x8*)&as[(wm + i * 16 + lr) * 32 + px * 8];
            bfr[i] = *(const f16x8*)&bs[(wn + i * 16 + lr) * 32 + px * 8];
        }
#pragma unroll
        for (int i = 0; i < 4; ++i)
#pragma unroll
            for (int j = 0; j < 4; ++j)
                acc[i][j] = __builtin_amdgcn_mfma_f32_16x16x32_f16(af[i], bfr[j], acc[i][j], 0, 0, 0);
    }

    if constexpr (EPI == 0) {
#pragma unroll
        for (int i = 0; i < 4; ++i)
#pragma unroll
            for (int j = 0; j < 4; ++j) {
                int col = n0 + wn + j * 16 + lr;
                float bv = a.bias ? a.bias[col] : 0.f;
#pragma unroll
                for (int r = 0; r < 4; ++r) {
                    int rowg = m0 + wm + i * 16 + kg * 4 + r;
                    if (rowg < a.M) {
                        float v = acc[i][j][r] + bv;
                        if (a.Cf) a.Cf[(size_t)rowg * a.ldc + col] = v;
                        if (a.Ch) a.Ch[(size_t)rowg * a.ldc + col] = (f16)v;
                    }
                }
            }
    } else if constexpr (EPI == 1) {
        int ub = (n0 >> 2) + (wave & 1) * 16 + lr;
        int c0 = n0 + wn + lr;
        float b0 = a.bias[c0];
        float b1 = a.bias[c0 + 16];
        float b2 = a.bias[c0 + 32];
        float b3 = a.bias[c0 + 48];
        float v0 = 0.f, v1 = 0.f, v2 = 0.f, v3 = 0.f;
        if (a.gvb) {
            v0 = a.gvb[c0];      v1 = a.gvb[c0 + 16];
            v2 = a.gvb[c0 + 32]; v3 = a.gvb[c0 + 48];
        }
#pragma unroll
        for (int i = 0; i < 4; ++i)
#pragma unroll
            for (int r = 0; r < 4; ++r) {
                int rowg = m0 + wm + i * 16 + kg * 4 + r;
                if (rowg < a.M) {
                    float ga0 = acc[i][0][r] + v0, ga1 = acc[i][1][r] + v1;
                    float ga2 = acc[i][2][r] + v2, ga3 = acc[i][3][r] + v3;
                    size_t gbase = (size_t)rowg * a.N + c0;
                    if (a.gst) {
                        a.gst[gbase]      = (f16)ga0;
                        a.gst[gbase + 16] = (f16)ga1;
                        a.gst[gbase + 32] = (f16)ga2;
                        a.gst[gbase + 48] = (f16)ga3;
                    }
                    if (a.gin) {
                        ga0 += (float)a.gin[gbase];
                        ga1 += (float)a.gin[gbase + 16];
                        ga2 += (float)a.gin[gbase + 32];
                        ga3 += (float)a.gin[gbase + 48];
                    }
                    float gi = ga0 + b0;
                    float gf = ga1 + b1;
                    float gg = ga2 + b2;
                    float go = ga3 + b3;
                    size_t off = (size_t)rowg * a.HH + ub;
                    float cn = sigf(gi) * tanh_f(gg);
                    if (!a.init) cn = fmaf(sigf(gf), (float)a.cb[off], cn);
                    if (!a.fin) a.cb[off] = (f16)cn;   // final step: c is dead
                    a.hb[off] = (f16)(sigf(go) * tanh_f(cn));
                }
            }
    } else {
#pragma unroll
        for (int i = 0; i < 4; ++i)
#pragma unroll
            for (int j = 0; j < 4; ++j) {
                int col = n0 + wn + j * 16 + lr;
#pragma unroll
                for (int r = 0; r < 4; ++r) {
                    int rowg = m0 + wm + i * 16 + kg * 4 + r;
                    if (rowg < a.M) {
                        float xv = (float)a.xff[(size_t)(rowg >> 2) * H + col];
                        float cv = a.cch[(size_t)rowg * H + col];
                        a.fcm[(size_t)rowg * H + col] =
                            (f16)(cv * sigf(xv + acc[i][j][r]));
                    }
                }
            }
    }
}

// ================= 128x128 tile, 256 thr (pair: u | f) =====================
template<int EPI>
__global__ __launch_bounds__(256) void gemm_pair(GArg u, GArg f, int split)
{
    __shared__ f16 As[2][128 * 32];
    __shared__ f16 Bs[2][128 * 32];
    const int tid = threadIdx.x;

    const int gX = gridDim.x, gY = gridDim.y;
    const int orig = blockIdx.y * gX + blockIdx.x;
    const int gXf = gX - split;
    const int nwgU = split * gY, nwgF = gXf * gY;

    int bx, by, isU;
    if (((nwgU | nwgF) & 7) == 0) {
        int cu = nwgU >> 3, cf = nwgF >> 3;
        int xcd = orig & 7, rem = orig >> 3;
        if (rem < cu) { int lid = xcd * cu + rem;        isU = 1; by = lid / split; bx = lid % split; }
        else          { int lid = xcd * cf + (rem - cu); isU = 0; by = lid / gXf;  bx = lid % gXf; }
    } else {
        const int nwg = gX * gY;
        const int q = nwg >> 3, r = nwg & 7;
        const int xcd = orig & 7, rem = orig >> 3;
        const int wgid = (xcd < r ? xcd * (q + 1) : r * (q + 1) + (xcd - r) * q) + rem;
        int bx0 = wgid % gX; by = wgid / gX;
        isU = (bx0 < split);
        bx = isU ? bx0 : bx0 - split;
    }
    const GArg a = isU ? u : f;        // uniform scalar select

    const int m0 = by * 128, n0 = bx * 128;
    const int wave = tid >> 6, lane = tid & 63;
    const int wm = (wave >> 1) * 64, wn = (wave & 1) * 64;
    const int lr = lane & 15, kg = lane >> 4;
    const int px = kg ^ ((lr >> 1) & 3);

    f32x4 acc[4][4];
#pragma unroll
    for (int i = 0; i < 4; ++i)
#pragma unroll
        for (int j = 0; j < 4; ++j) acc[i][j] = (f32x4){0.f, 0.f, 0.f, 0.f};

    const int nt1 = a.K0 >> 5;
    const int nt = nt1 + (a.K1 >> 5);

    auto stage = [&](int t, int b) {
        const f16* Ap; const f16* Bp; int la, lb, k0;
        if (t < nt1) { Ap = a.A0; Bp = a.B0; la = a.la0; lb = a.lb0; k0 = t * 32; }
        else         { Ap = a.A1; Bp = a.B1; la = a.la1; lb = a.lb1; k0 = (t - nt1) * 32; }
#pragma unroll
        for (int v = 0; v < 2; ++v) {
            int idx = v * 256 + tid;
            int row = idx >> 2, cph = idx & 3;
            int clog = cph ^ ((row >> 1) & 3);
            int ar = m0 + row;
            if (ar >= a.M) ar = a.M - 1;
            gload16(Ap + (size_t)ar * la + k0 + clog * 8, &As[b][idx * 8]);
            gload16(Bp + (size_t)(n0 + row) * lb + k0 + clog * 8, &Bs[b][idx * 8]);
        }
    };

    stage(0, 0);
    for (int t = 0; t < nt; ++t) {
        __syncthreads();
        if (t + 1 < nt) stage(t + 1, (t + 1) & 1);
        const f16* as = As[t & 1];
        const f16* bs = Bs[t & 1];
        f16x8 af[4], bfr[4];
#pragma unroll
        for (int i = 0; i < 4; ++i) {
            af[i]  = *(const f16x8*)&as[(wm + i * 16 + lr) * 32 + px * 8];
            bfr[i] = *(const f16x8*)&bs[(wn + i * 16 + lr) * 32 + px * 8];
        }
#pragma unroll
        for (int i = 0; i < 4; ++i)
#pragma unroll
            for (int j = 0; j < 4; ++j)
                acc[i][j] = __builtin_amdgcn_mfma_f32_16x16x32_f16(af[i], bfr[j], acc[i][j], 0, 0, 0);
    }

    if constexpr (EPI == 0) {
#pragma unroll
        for (int i = 0; i < 4; ++i)
#pragma unroll
            for (int j = 0; j < 4; ++j) {
                int col = n0 + wn + j * 16 + lr;
                float bv = a.bias ? a.bias[col] : 0.f;
#pragma unroll
                for (int r = 0; r < 4; ++r) {
                    int rowg = m0 + wm + i * 16 + kg * 4 + r;
                    if (rowg < a.M) {
                        float v = acc[i][j][r] + bv;
                        if (a.Cf) a.Cf[(size_t)rowg * a.ldc + col] = v;
                        if (a.Ch) a.Ch[(size_t)rowg * a.ldc + col] = (f16)v;
                    }
                }
            }
    } else {
        int ub = (n0 >> 2) + (wave & 1) * 16 + lr;
        int c0 = n0 + wn + lr;
        float b0 = a.bias[c0];
        float b1 = a.bias[c0 + 16];
        float b2 = a.bias[c0 + 32];
        float b3 = a.bias[c0 + 48];
        float v0 = 0.f, v1 = 0.f, v2 = 0.f, v3 = 0.f;
        if (a.gvb) {
            v0 = a.gvb[c0];      v1 = a.gvb[c0 + 16];
            v2 = a.gvb[c0 + 32]; v3 = a.gvb[c0 + 48];
        }
#pragma unroll
        for (int i = 0; i < 4; ++i)
#pragma unroll
            for (int r = 0; r < 4; ++r) {
                int rowg = m0 + wm + i * 16 + kg * 4 + r;
                if (rowg < a.M) {
                    float ga0 = acc[i][0][r] + v0, ga1 = acc[i][1][r] + v1;
                    float ga2 = acc[i][2][r] + v2, ga3 = acc[i][3][r] + v3;
                    size_t gbase = (size_t)rowg * a.N + c0;
                    if (a.gst) {
                        a.gst[gbase]      = (f16)ga0;
                        a.gst[gbase + 16] = (f16)ga1;
                        a.gst[gbase + 32] = (f16)ga2;
                        a.gst[gbase + 48] = (f16)ga3;
                    }
                    if (a.gin) {
                        ga0 += (float)a.gin[gbase];
                        ga1 += (float)a.gin[gbase + 16];
                        ga2 += (float)a.gin[gbase + 32];
                        ga3 += (float)a.gin[gbase + 48];
                    }
                    float gi = ga0 + b0;
                    float gf = ga1 + b1;
                    float gg = ga2 + b2;
                    float go = ga3 + b3;
                    size_t off = (size_t)rowg * a.HH + ub;
                    float cn = sigf(gi) * tanh_f(gg);
                    if (!a.init) cn = fmaf(sigf(gf), (float)a.cb[off], cn);
                    if (!a.fin) a.cb[off] = (f16)cn;   // final step: c is dead
                    a.hb[off] = (f16)(sigf(go) * tanh_f(cn));
                }
            }
    }
}

// ================= 128x256 tile, 512 thr (single) ==========================
template<int EPI>
__global__ __launch_bounds__(512) void gemm_big(GArg a)
{
    __shared__ f16 As[2][128 * 32];
    __shared__ f16 Bs[2][256 * 32];
    const int tid = threadIdx.x;

    const int gX = gridDim.x;
    const int nwg = gX * gridDim.y;
    const int orig = blockIdx.y * gX + blockIdx.x;
    const int q = nwg >> 3, r = nwg & 7;
    const int xcd = orig & 7, rem = orig >> 3;
    const int wgid = (xcd < r ? xcd * (q + 1) : r * (q + 1) + (xcd - r) * q) + rem;
    const int bx = wgid % gX, by = wgid / gX;

    const int m0 = by * 128, n0 = bx * 256;
    const int wave = tid >> 6, lane = tid & 63;
    const int wm = (wave >> 2) * 64, wn = (wave & 3) * 64;
    const int lr = lane & 15, kg = lane >> 4;
    const int px = kg ^ ((lr >> 1) & 3);

    f32x4 acc[4][4];
#pragma unroll
    for (int i = 0; i < 4; ++i)
#pragma unroll
        for (int j = 0; j < 4; ++j) acc[i][j] = (f32x4){0.f, 0.f, 0.f, 0.f};

    const int nt1 = a.K0 >> 5;
    const int nt = nt1 + (a.K1 >> 5);

    auto stage = [&](int t, int b) {
        const f16* Ap; const f16* Bp; int la, lb, k0;
        if (t < nt1) { Ap = a.A0; Bp = a.B0; la = a.la0; lb = a.lb0; k0 = t * 32; }
        else         { Ap = a.A1; Bp = a.B1; la = a.la1; lb = a.lb1; k0 = (t - nt1) * 32; }
        {
            int idx = tid;
            int row = idx >> 2, cph = idx & 3;
            int clog = cph ^ ((row >> 1) & 3);
            int ar = m0 + row;
            if (ar >= a.M) ar = a.M - 1;
            gload16(Ap + (size_t)ar * la + k0 + clog * 8, &As[b][idx * 8]);
        }
#pragma unroll
        for (int v = 0; v < 2; ++v) {
            int idx = v * 512 + tid;
            int row = idx >> 2, cph = idx & 3;
            int clog = cph ^ ((row >> 1) & 3);
            gload16(Bp + (size_t)(n0 + row) * lb + k0 + clog * 8, &Bs[b][idx * 8]);
        }
    };

    stage(0, 0);
    for (int t = 0; t < nt; ++t) {
        __syncthreads();
        if (t + 1 < nt) stage(t + 1, (t + 1) & 1);
        const f16* as = As[t & 1];
        const f16* bs = Bs[t & 1];
        f16x8 af[4], bfr[4];
#pragma unroll
        for (int i = 0; i < 4; ++i) {
            af[i]  = *(const f16x8*)&as[(wm + i * 16 + lr) * 32 + px * 8];
            bfr[i] = *(const f16x8*)&bs[(wn + i * 16 + lr) * 32 + px * 8];
        }
#pragma unroll
        for (int i = 0; i < 4; ++i)
#pragma unroll
            for (int j = 0; j < 4; ++j)
                acc[i][j] = __builtin_amdgcn_mfma_f32_16x16x32_f16(af[i], bfr[j], acc[i][j], 0, 0, 0);
    }

    if constexpr (EPI == 0) {
#pragma unroll
        for (int i = 0; i < 4; ++i)
#pragma unroll
            for (int j = 0; j < 4; ++j) {
                int col = n0 + wn + j * 16 + lr;
                float bv = a.bias ? a.bias[col] : 0.f;
#pragma unroll
                for (int r = 0; r < 4; ++r) {
                    int rowg = m0 + wm + i * 16 + kg * 4 + r;
                    if (rowg < a.M) {
                        float v = acc[i][j][r] + bv;
                        if (a.Cf) a.Cf[(size_t)rowg * a.ldc + col] = v;
                        if (a.Ch) a.Ch[(size_t)rowg * a.ldc + col] = (f16)v;
                    }
                }
            }
    } else if constexpr (EPI == 1) {
        int ub = (n0 >> 2) + (wave & 3) * 16 + lr;
        int c0 = n0 + wn + lr;
        float b0 = a.bias[c0];
        float b1 = a.bias[c0 + 16];
        float b2 = a.bias[c0 + 32];
        float b3 = a.bias[c0 + 48];
        float v0 = 0.f, v1 = 0.f, v2 = 0.f, v3 = 0.f;
        if (a.gvb) {
            v0 = a.gvb[c0];      v1 = a.gvb[c0 + 16];
            v2 = a.gvb[c0 + 32]; v3 = a.gvb[c0 + 48];
        }
#pragma unroll
        for (int i = 0; i < 4; ++i)
#pragma unroll
            for (int r = 0; r < 4; ++r) {
                int rowg = m0 + wm + i * 16 + kg * 4 + r;
                if (rowg < a.M) {
                    float ga0 = acc[i][0][r] + v0, ga1 = acc[i][1][r] + v1;
                    float ga2 = acc[i][2][r] + v2, ga3 = acc[i][3][r] + v3;
                    size_t gbase = (size_t)rowg * a.N + c0;
                    if (a.gst) {
                        a.gst[gbase]      = (f16)ga0;
                        a.gst[gbase + 16] = (f16)ga1;
                        a.gst[gbase + 32] = (f16)ga2;
                        a.gst[gbase + 48] = (f16)ga3;
                    }
                    if (a.gin) {
                        ga0 += (float)a.gin[gbase];
                        ga1 += (float)a.gin[gbase + 16];
                        ga2 += (float)a.gin[gbase + 32];
                        ga3 += (float)a.gin[gbase + 48];
                    }
                    float gi = ga0 + b0;
                    float gf = ga1 + b1;
                    float gg = ga2 + b2;
                    float go = ga3 + b3;
                    size_t off = (size_t)rowg * a.HH + ub;
                    float cn = sigf(gi) * tanh_f(gg);
                    if (!a.init) cn = fmaf(sigf(gf), (float)a.cb[off], cn);
                    if (!a.fin) a.cb[off] = (f16)cn;   // final step: c is dead
                    a.hb[off] = (f16)(sigf(go) * tanh_f(cn));
                }
            }
    } else {
#pragma unroll
        for (int i = 0; i < 4; ++i)
#pragma unroll
            for (int j = 0; j < 4; ++j) {
                int col = n0 + wn + j * 16 + lr;
#pragma unroll
                for (int r = 0; r < 4; ++r) {
                    int rowg = m0 + wm + i * 16 + kg * 4 + r;
                    if (rowg < a.M) {
                        float xv = (float)a.xff[(size_t)(rowg >> 2) * H + col];
                        float cv = a.cch[(size_t)rowg * H + col];
                        a.fcm[(size_t)rowg * H + col] =
                            (f16)(cv * sigf(xv + acc[i][j][r]));
                    }
                }
            }
    }
}

// ================= 128x256 tile, 512 thr (pair: u | f) =====================
template<int EPI>
__global__ __launch_bounds__(512) void gemm_pair_big(GArg u, GArg f, int split)
{
    __shared__ f16 As[2][128 * 32];
    __shared__ f16 Bs[2][256 * 32];
    const int tid = threadIdx.x;

    const int gX = gridDim.x, gY = gridDim.y;
    const int orig = blockIdx.y * gX + blockIdx.x;
    const int gXf = gX - split;
    const int nwgU = split * gY, nwgF = gXf * gY;

    int bx, by, isU;
    if (((nwgU | nwgF) & 7) == 0) {
        int cu = nwgU >> 3, cf = nwgF >> 3;
        int xcd = orig & 7, rem = orig >> 3;
        if (rem < cu) { int lid = xcd * cu + rem;        isU = 1; by = lid / split; bx = lid % split; }
        else          { int lid = xcd * cf + (rem - cu); isU = 0; by = lid / gXf;  bx = lid % gXf; }
    } else {
        const int nwg = gX * gY;
        const int q = nwg >> 3, r = nwg & 7;
        const int xcd = orig & 7, rem = orig >> 3;
        const int wgid = (xcd < r ? xcd * (q + 1) : r * (q + 1) + (xcd - r) * q) + rem;
        int bx0 = wgid % gX; by = wgid / gX;
        isU = (bx0 < split);
        bx = isU ? bx0 : bx0 - split;
    }
    const GArg a = isU ? u : f;        // uniform scalar select

    const int m0 = by * 128, n0 = bx * 256;
    const int wave = tid >> 6, lane = tid & 63;
    const int wm = (wave >> 2) * 64, wn = (wave & 3) * 64;
    const int lr = lane & 15, kg = lane >> 4;
    const int px = kg ^ ((lr >> 1) & 3);

    f32x4 acc[4][4];
#pragma unroll
    for (int i = 0; i < 4; ++i)
#pragma unroll
        for (int j = 0; j < 4; ++j) acc[i][j] = (f32x4){0.f, 0.f, 0.f, 0.f};

    const int nt1 = a.K0 >> 5;
    const int nt = nt1 + (a.K1 >> 5);

    auto stage = [&](int t, int b) {
        const f16* Ap; const f16* Bp; int la, lb, k0;
        if (t < nt1) { Ap = a.A0; Bp = a.B0; la = a.la0; lb = a.lb0; k0 = t * 32; }
        else         { Ap = a.A1; Bp = a.B1; la = a.la1; lb = a.lb1; k0 = (t - nt1) * 32; }
        {
            int idx = tid;
            int row = idx >> 2, cph = idx & 3;
            int clog = cph ^ ((row >> 1) & 3);
            int ar = m0 + row;
            if (ar >= a.M) ar = a.M - 1;
            gload16(Ap + (size_t)ar * la + k0 + clog * 8, &As[b][idx * 8]);
        }
#pragma unroll
        for (int v = 0; v < 2; ++v) {
            int idx = v * 512 + tid;
            int row = idx >> 2, cph = idx & 3;
            int clog = cph ^ ((row >> 1) & 3);
            gload16(Bp + (size_t)(n0 + row) * lb + k0 + clog * 8, &Bs[b][idx * 8]);
        }
    };

    stage(0, 0);
    for (int t = 0; t < nt; ++t) {
        __syncthreads();
        if (t + 1 < nt) stage(t + 1, (t + 1) & 1);
        const f16* as = As[t & 1];
        const f16* bs = Bs[t & 1];
        f16x8 af[4], bfr[4];
#pragma unroll
        for (int i = 0; i < 4; ++i) {
            af[i]  = *(const f16x8*)&as[(wm + i * 16 + lr) * 32 + px * 8];
            bfr[i] = *(const f16x8*)&bs[(wn + i * 16 + lr) * 32 + px * 8];
        }
#pragma unroll
        for (int i = 0; i < 4; ++i)
#pragma unroll
            for (int j = 0; j < 4; ++j)
                acc[i][j] = __builtin_amdgcn_mfma_f32_16x16x32_f16(af[i], bfr[j], acc[i][j], 0, 0, 0);
    }

    if constexpr (EPI == 0) {
#pragma unroll
        for (int i = 0; i < 4; ++i)
#pragma unroll
            for (int j = 0; j < 4; ++j) {
                int col = n0 + wn + j * 16 + lr;
                float bv = a.bias ? a.bias[col] : 0.f;
#pragma unroll
                for (int r = 0; r < 4; ++r) {
                    int rowg = m0 + wm + i * 16 + kg * 4 + r;
                    if (rowg < a.M) {
                        float v = acc[i][j][r] + bv;
                        if (a.Cf) a.Cf[(size_t)rowg * a.ldc + col] = v;
                        if (a.Ch) a.Ch[(size_t)rowg * a.ldc + col] = (f16)v;
                    }
                }
            }
    } else {
        int ub = (n0 >> 2) + (wave & 3) * 16 + lr;
        int c0 = n0 + wn + lr;
        float b0 = a.bias[c0];
        float b1 = a.bias[c0 + 16];
        float b2 = a.bias[c0 + 32];
        float b3 = a.bias[c0 + 48];
        float v0 = 0.f, v1 = 0.f, v2 = 0.f, v3 = 0.f;
        if (a.gvb) {
            v0 = a.gvb[c0];      v1 = a.gvb[c0 + 16];
            v2 = a.gvb[c0 + 32]; v3 = a.gvb[c0 + 48];
        }
#pragma unroll
        for (int i = 0; i < 4; ++i)
#pragma unroll
            for (int r = 0; r < 4; ++r) {
                int rowg = m0 + wm + i * 16 + kg * 4 + r;
                if (rowg < a.M) {
                    float ga0 = acc[i][0][r] + v0, ga1 = acc[i][1][r] + v1;
                    float ga2 = acc[i][2][r] + v2, ga3 = acc[i][3][r] + v3;
                    size_t gbase = (size_t)rowg * a.N + c0;
                    if (a.gst) {
                        a.gst[gbase]      = (f16)ga0;
                        a.gst[gbase + 16] = (f16)ga1;
                        a.gst[gbase + 32] = (f16)ga2;
                        a.gst[gbase + 48] = (f16)ga3;
                    }
                    if (a.gin) {
                        ga0 += (float)a.gin[gbase];
                        ga1 += (float)a.gin[gbase + 16];
                        ga2 += (float)a.gin[gbase + 32];
                        ga3 += (float)a.gin[gbase + 48];
                    }
                    float gi = ga0 + b0;
                    float gf = ga1 + b1;
                    float gg = ga2 + b2;
                    float go = ga3 + b3;
                    size_t off = (size_t)rowg * a.HH + ub;
                    float cn = sigf(gi) * tanh_f(gg);
                    if (!a.init) cn = fmaf(sigf(gf), (float)a.cb[off], cn);
                    if (!a.fin) a.cb[off] = (f16)cn;   // final step: c is dead
                    a.hb[off] = (f16)(sigf(go) * tanh_f(cn));
                }
            }
    }
}

// ---------------- f32 tiled NT GEMM (prep only: folded weights) ----------------
__global__ __launch_bounds__(256) void gemm_nt_f32(
    const float* __restrict__ A, int lda,
    const float* __restrict__ B, int ldb,
    float* __restrict__ C, int ldc, int M, int N, int K)
{
    __shared__ float As[16][128];
    __shared__ float Bs[16][128];
    const int m0 = blockIdx.y * 128, n0 = blockIdx.x * 128;
    const int tid = threadIdx.x;
    const int tx = tid & 15, ty = tid >> 4;
    float acc[8][8];
#pragma unroll
    for (int i = 0; i < 8; ++i)
#pragma unroll
        for (int j = 0; j < 8; ++j) acc[i][j] = 0.0f;
    for (int k0 = 0; k0 < K; k0 += 16) {
#pragma unroll
        for (int v = 0; v < 2; ++v) {
            int idx = tid + v * 256;
            int row = idx >> 2, c4 = idx & 3;
            float4 av = make_float4(0, 0, 0, 0);
            int gm = m0 + row;
            if (gm < M) av = *(const float4*)&A[(size_t)gm * lda + k0 + c4 * 4];
            As[c4 * 4 + 0][row] = av.x; As[c4 * 4 + 1][row] = av.y;
            As[c4 * 4 + 2][row] = av.z; As[c4 * 4 + 3][row] = av.w;
            float4 bv = make_float4(0, 0, 0, 0);
            int gn = n0 + row;
            if (gn < N) bv = *(const float4*)&B[(size_t)gn * ldb + k0 + c4 * 4];
            Bs[c4 * 4 + 0][row] = bv.x; Bs[c4 * 4 + 1][row] = bv.y;
            Bs[c4 * 4 + 2][row] = bv.z; Bs[c4 * 4 + 3][row] = bv.w;
        }
        __syncthreads();
#pragma unroll
        for (int kk = 0; kk < 16; ++kk) {
            float4 a0 = *(const float4*)&As[kk][ty * 8];
            float4 a1 = *(const float4*)&As[kk][ty * 8 + 4];
            float4 b0 = *(const float4*)&Bs[kk][tx * 8];
            float4 b1 = *(const float4*)&Bs[kk][tx * 8 + 4];
            float av[8] = { a0.x,a0.y,a0.z,a0.w,a1.x,a1.y,a1.z,a1.w };
            float bv[8] = { b0.x,b0.y,b0.z,b0.w,b1.x,b1.y,b1.z,b1.w };
#pragma unroll
            for (int i = 0; i < 8; ++i)
#pragma unroll
                for (int j = 0; j < 8; ++j)
                    acc[i][j] = fmaf(av[i], bv[j], acc[i][j]);
        }
        __syncthreads();
    }
#pragma unroll
    for (int i = 0; i < 8; ++i) {
        int gm = m0 + ty * 8 + i;
        if (gm >= M) break;
#pragma unroll
        for (int j = 0; j < 8; ++j) {
            int gn = n0 + tx * 8 + j;
            if (gn < N) C[(size_t)gm * ldc + gn] = acc[i][j];
        }
    }
}

// ---------------- elementwise / prep kernels ----------------

// leaves: iou f16 [count,768] -> h f16, c f32 (pointers pre-offset)
__global__ __launch_bounds__(256) void leaf_apply(
    const f16* __restrict__ iou, f16* __restrict__ hh, float* __restrict__ c,
    int count)
{
    int idx = blockIdx.x * 256 + threadIdx.x;
    int tot = count * (H / 4);
    if (idx >= tot) return;
    int row = idx >> 6;
    int c4 = (idx & 63) * 4;
    const f16* r = iou + (size_t)row * H3;
    f16x4 vi = *(const f16x4*)&r[c4];
    f16x4 vo = *(const f16x4*)&r[H + c4];
    f16x4 vu = *(const f16x4*)&r[2 * H + c4];
    size_t off = (size_t)row * H + c4;
    float cc[4]; f16x4 hq;
#pragma unroll
    for (int j = 0; j < 4; ++j) {
        cc[j] = sigf((float)vi[j]) * tanh_f((float)vu[j]);
        hq[j] = (f16)(sigf((float)vo[j]) * tanh_f(cc[j]));
    }
    *(float4*)&c[off] = make_float4(cc[0], cc[1], cc[2], cc[3]);
    *(f16x4*)&hh[off] = hq;
}

// internal apply: all f16 inputs; h f16 + c f32 out (pointers pre-offset)
__global__ __launch_bounds__(256) void node_apply(
    const f16* __restrict__ xiou, const f16* __restrict__ h_uh,
    const f16* __restrict__ hfc, f16* __restrict__ hh, float* __restrict__ c,
    int Cn)
{
    int idx = blockIdx.x * 256 + threadIdx.x;
    int tot = Cn * (H / 4);
    if (idx >= tot) return;
    int row = idx >> 6;
    int c4 = (idx & 63) * 4;
    const f16* xr = xiou + (size_t)row * H3;
    const f16* ur = h_uh + (size_t)row * H3;
    f16x4 xi = *(const f16x4*)&xr[c4];
    f16x4 xo = *(const f16x4*)&xr[H + c4];
    f16x4 xu = *(const f16x4*)&xr[2 * H + c4];
    f16x4 ui = *(const f16x4*)&ur[c4];
    f16x4 uo = *(const f16x4*)&ur[H + c4];
    f16x4 uu = *(const f16x4*)&ur[2 * H + c4];
    f16x4 fv = *(const f16x4*)&hfc[(size_t)row * H + c4];
    size_t off = (size_t)row * H + c4;
    float cc[4]; f16x4 hq;
#pragma unroll
    for (int j = 0; j < 4; ++j) {
        float iv = (float)xi[j] + (float)ui[j];
        float ov = (float)xo[j] + (float)uo[j];
        float uv = (float)xu[j] + (float)uu[j];
        float cv = sigf(iv) * tanh_f(uv) + (float)fv[j];
        cc[j] = cv;
        hq[j] = (f16)(sigf(ov) * tanh_f(cv));
    }
    *(float4*)&c[off] = make_float4(cc[0], cc[1], cc[2], cc[3]);
    *(f16x4*)&hh[off] = hq;
}

__global__ __launch_bounds__(256) void bias_sum(
    const float* __restrict__ a, const float* __restrict__ b, float* __restrict__ o, int n)
{
    int i = blockIdx.x * 256 + threadIdx.x;
    if (i < n) o[i] = a[i] + b[i];
}

// y[m] = dot(A[m,:], x) — folded-bias vector (prep only)
__global__ __launch_bounds__(256) void matvec_f32(
    const float* __restrict__ A, const float* __restrict__ x,
    float* __restrict__ y, int M, int K)
{
    int m = blockIdx.x * 256 + threadIdx.x;
    if (m >= M) return;
    const float* r = A + (size_t)m * K;
    float s = 0.f;
    for (int k = 0; k < K; k += 4) {
        float4 a = *(const float4*)&r[k];
        float4 b = *(const float4*)&x[k];
        s += a.x * b.x + a.y * b.y + a.z * b.z + a.w * b.w;
    }
    y[m] = s;
}

__global__ __launch_bounds__(256) void cvt_f16(
    const float* __restrict__ in, f16* __restrict__ out, int n)
{
    int idx = blockIdx.x * 256 + threadIdx.x;
    if (idx * 4 >= n) return;
    float4 v = *(const float4*)&in[idx * 4];
    f16x4 o; o[0] = (f16)v.x; o[1] = (f16)v.y; o[2] = (f16)v.z; o[3] = (f16)v.w;
    *(f16x4*)&out[idx * 4] = o;
}

// gate-permute rows of src [GUH x ld] (taking K cols) -> dst f16 [GUH x K]
__global__ __launch_bounds__(256) void permute_cvt(
    const float* __restrict__ src, f16* __restrict__ dst, int HH, int K, int ld, int tot4)
{
    int idx = blockIdx.x * 256 + threadIdx.x;
    if (idx >= tot4) return;
    int kq = K >> 2;
    int m = idx / kq;
    int k4 = (idx - m * kq) * 4;
    int gate = (m >> 4) & 3;
    int unit = (m >> 7) * 32 + ((m >> 6) & 1) * 16 + (m & 15);
    float4 v = *(const float4*)&src[(size_t)(gate * HH + unit) * ld + k4];
    f16x4 o; o[0] = (f16)v.x; o[1] = (f16)v.y; o[2] = (f16)v.z; o[3] = (f16)v.w;
    *(f16x4*)&dst[(size_t)m * K + k4] = o;
}

__global__ __launch_bounds__(256) void permute_bias(
    const float* __restrict__ src, float* __restrict__ dst, int HH, int n)
{
    int m = blockIdx.x * 256 + threadIdx.x;
    if (m >= n) return;
    int gate = (m >> 4) & 3;
    int unit = (m >> 7) * 32 + ((m >> 6) & 1) * 16 + (m & 15);
    dst[m] = src[gate * HH + unit];
}

__global__ __launch_bounds__(256) void transpose_f32(
    const float* __restrict__ in, float* __restrict__ out)
{
    int idx = blockIdx.x * 256 + threadIdx.x;
    if (idx >= H3 * E) return;
    int r = idx >> 8, c = idx & 255;
    out[(size_t)c * H3 + r] = in[idx];
}

__global__ __launch_bounds__(256) void ln_tanh(
    float* __restrict__ y, const float* __restrict__ g, const float* __restrict__ b,
    int Nrows)
{
    int wave = threadIdx.x >> 6;
    int lane = threadIdx.x & 63;
    int row = blockIdx.x * 4 + wave;
    if (row >= Nrows) return;
    float* yr = y + (size_t)row * DEC;
    float4 v0 = *(const float4*)&yr[lane * 8];
    float4 v1 = *(const float4*)&yr[lane * 8 + 4];
    float s = v0.x + v0.y + v0.z + v0.w + v1.x + v1.y + v1.z + v1.w;
    float s2 = v0.x * v0.x + v0.y * v0.y + v0.z * v0.z + v0.w * v0.w +
               v1.x * v1.x + v1.y * v1.y + v1.z * v1.z + v1.w * v1.w;
#pragma unroll
    for (int off = 32; off; off >>= 1) {
        s += __shfl_xor(s, off);
        s2 += __shfl_xor(s2, off);
    }
    float m = s * (1.0f / DEC);
    float var = s2 * (1.0f / DEC) - m * m;
    float rstd = rsqrtf(var + 1e-5f);
    float vals[8] = { v0.x,v0.y,v0.z,v0.w,v1.x,v1.y,v1.z,v1.w };
    float o[8];
#pragma unroll
    for (int j = 0; j < 8; ++j) {
        int colj = lane * 8 + j;
        o[j] = tanh_f((vals[j] - m) * rstd * g[colj] + b[colj]);
    }
    *(float4*)&yr[lane * 8] = make_float4(o[0], o[1], o[2], o[3]);
    *(float4*)&yr[lane * 8 + 4] = make_float4(o[4], o[5], o[6], o[7]);
}

// ---------------- host ----------------
extern "C" void kernel_launch(void* const* d_in, const int* in_sizes, int n_in,
                              void* d_out, int out_size, void* d_ws, size_t ws_size,
                              hipStream_t stream)
{
    (void)in_sizes; (void)n_in; (void)out_size;
    const float* embed   = (const float*)d_in[0];
    const float* W_iou_w = (const float*)d_in[1];
    const float* W_iou_b = (const float*)d_in[2];
    const float* U_iou_w = (const float*)d_in[3];
    const float* W_f_w   = (const float*)d_in[4];
    const float* W_f_b   = (const float*)d_in[5];
    const float* U_f_w   = (const float*)d_in[6];
    const float* uh_wih  = (const float*)d_in[7];
    const float* uh_whh  = (const float*)d_in[8];
    const float* uh_bih  = (const float*)d_in[9];
    const float* uh_bhh  = (const float*)d_in[10];
    const float* fc_wih  = (const float*)d_in[11];
    const float* fc_whh  = (const float*)d_in[12];
    const float* fc_bih  = (const float*)d_in[13];
    const float* fc_bhh  = (const float*)d_in[14];
    const float* out_w   = (const float*)d_in[15];
    const float* out_b   = (const float*)d_in[16];
    const float* ln_g    = (const float*)d_in[17];
    const float* ln_b    = (const float*)d_in[18];

    float* out  = (float*)d_out;
    float* cbuf = out;

    float* ws = (float*)d_ws;
    size_t o = 0;
    f16* embed_h = (f16*)(ws + o); o += (size_t)NNODES * E / 2;
    f16* hbuf_h  = (f16*)(ws + o); o += (size_t)NNODES * H / 2;
    f16* wiou_h  = (f16*)(ws + o); o += (size_t)H3 * E / 2;
    f16* wf_h    = (f16*)(ws + o); o += (size_t)H * E / 2;
    f16* uf_h    = (f16*)(ws + o); o += (size_t)H * H / 2;
    f16* wih_p   = (f16*)(ws + o); o += (size_t)GUH * H3 / 2;
    f16* whh_p   = (f16*)(ws + o); o += (size_t)GUH * H3 / 2;
    f16* fih_p   = (f16*)(ws + o); o += (size_t)GFC * H / 2;
    f16* fhh_p   = (f16*)(ws + o); o += (size_t)GFC * H / 2;
    f16* ow_h    = (f16*)(ws + o); o += (size_t)DEC * H / 2;
    f16* fold_p  = (f16*)(ws + o); o += (size_t)GUH * E / 2;
    f16* fold2_p = (f16*)(ws + o); o += (size_t)GUH * E / 2;   // Wih·W_iou folded
    float* fold_ff = ws + o; o += (size_t)GUH * 512;           // merged fold out [GUH x 512]
    float* UtW     = ws + o; o += (size_t)512 * H3;            // [U_iou^T ; W_iou^T]
    float* bsu    = ws + o; o += GUH;
    float* bsf    = ws + o; o += GFC;
    float* pbu    = ws + o; o += GUH;
    float* pbf    = ws + o; o += GFC;
    float* gvbr   = ws + o; o += GUH;                          // Wih·b_iou raw
    float* gvbu   = ws + o; o += GUH;                          // permuted

    // per-chunk f32 words/row:
    // xiou_h 384 + xf_h 128 + gbuf 3072 + hfc0 128 + hfc1 128 + cfc 128
    // + huh0 384 + huh1 384 + c_uh 384 + fcm_h 512 = 5632
    size_t avail = ws_size / 4;
    long long room = (long long)avail - (long long)o - 8192;
    long long Cl = room / 5632;
    int C;
    if (Cl >= 16384) C = 16384;
    else if (Cl <= 256) C = 256;
    else C = (int)((Cl / 256) * 256);

    f16*   xiou_h = (f16*)(ws + o); o += (size_t)C * H3 / 2;
    f16*   xf_h   = (f16*)(ws + o); o += (size_t)C * H / 2;
    float* gbuf   = ws + o; o += (size_t)4 * C * H3;   // leaf iou f16 region; later tok store
    f16*   hfc0   = (f16*)(ws + o); o += (size_t)C * H / 2;
    f16*   hfc1   = (f16*)(ws + o); o += (size_t)C * H / 2;
    f16*   cfc    = (f16*)(ws + o); o += (size_t)C * H / 2;   // f16 level-local c
    f16*   huh0   = (f16*)(ws + o); o += (size_t)C * H3 / 2;
    f16*   huh1   = (f16*)(ws + o); o += (size_t)C * H3 / 2;
    f16*   c_uh   = (f16*)(ws + o); o += (size_t)C * H3 / 2;  // f16 level-local c
    f16*   fcm_h  = (f16*)(ws + o); o += (size_t)4 * C * H / 2;

    f16* huh[2] = { huh0, huh1 };
    f16* hfc[2] = { hfc0, hfc1 };

    // leaf iou (f16) and tok_ih stores (f16) carved from gbuf:
    f16* leaf_h = (f16*)gbuf;                              // [4C x 768] f16
    f16* toku   = (f16*)gbuf;                              // [C x 3072] f16 (after leaves)
    f16* tokf   = (f16*)(gbuf + (size_t)C * 1536);         // [C x 1024] f16

    auto L0 = [&](const GArg& a) {
        if (a.M >= 8192)
            gemm_big<0><<<dim3(a.N / 256, (a.M + 127) / 128), 512, 0, stream>>>(a);
        else
            gemm_one<0><<<dim3(a.N / 128, (a.M + 127) / 128), 256, 0, stream>>>(a);
    };
    auto P0 = [&](const GArg& u, const GArg& f) {
        if (u.M >= 8192)
            gemm_pair_big<0><<<dim3(u.N / 256 + f.N / 256, (u.M + 127) / 128), 512, 0, stream>>>(u, f, u.N / 256);
        else
            gemm_pair<0><<<dim3(u.N / 128 + f.N / 128, (u.M + 127) / 128), 256, 0, stream>>>(u, f, u.N / 128);
    };
    auto P1 = [&](const GArg& u, const GArg& f) {
        if (u.M >= 8192)
            gemm_pair_big<1><<<dim3(u.N / 256 + f.N / 256, (u.M + 127) / 128), 512, 0, stream>>>(u, f, u.N / 256);
        else
            gemm_pair<1><<<dim3(u.N / 128 + f.N / 128, (u.M + 127) / 128), 256, 0, stream>>>(u, f, u.N / 128);
    };

    // ---- prep ----
    auto CVT = [&](const float* s, f16* dv, int n) {
        cvt_f16<<<(n / 4 + 255) / 256, 256, 0, stream>>>(s, dv, n);
    };
    CVT(embed, embed_h, NNODES * E);
    CVT(W_iou_w, wiou_h, H3 * E);
    CVT(W_f_w, wf_h, H * E);
    CVT(U_f_w, uf_h, H * H);
    CVT(out_w, ow_h, DEC * H);
    permute_cvt<<<(GUH * H3 / 4 + 255) / 256, 256, 0, stream>>>(uh_wih, wih_p, H3, H3, H3, GUH * H3 / 4);
    permute_cvt<<<(GUH * H3 / 4 + 255) / 256, 256, 0, stream>>>(uh_whh, whh_p, H3, H3, H3, GUH * H3 / 4);
    permute_cvt<<<(GFC * H / 4 + 255) / 256, 256, 0, stream>>>(fc_wih, fih_p, H, H, H, GFC * H / 4);
    permute_cvt<<<(GFC * H / 4 + 255) / 256, 256, 0, stream>>>(fc_whh, fhh_p, H, H, H, GFC * H / 4);
    bias_sum<<<(GUH + 255) / 256, 256, 0, stream>>>(uh_bih, uh_bhh, bsu, GUH);
    bias_sum<<<(GFC + 255) / 256, 256, 0, stream>>>(fc_bih, fc_bhh, bsf, GFC);
    permute_bias<<<(GUH + 255) / 256, 256, 0, stream>>>(bsu, pbu, H3, GUH);
    permute_bias<<<(GFC + 255) / 256, 256, 0, stream>>>(bsf, pbf, H, GFC);
    // merged folds: UtW = [U_iou^T (rows 0..255) ; W_iou^T (rows 256..511)],
    // one N=512 gemm_nt (same wall time as N=256: parallelism-starved kernel),
    // then slice+permute. fold1 = Wih@U_iou (cols 0..255), fold2 = Wih@W_iou.
    transpose_f32<<<(H3 * E + 255) / 256, 256, 0, stream>>>(U_iou_w, UtW);
    transpose_f32<<<(H3 * E + 255) / 256, 256, 0, stream>>>(W_iou_w, UtW + (size_t)E * H3);
    {
        dim3 grid(512 / 128, GUH / 128);
        gemm_nt_f32<<<grid, 256, 0, stream>>>(uh_wih, H3, UtW, H3, fold_ff, 512, GUH, 512, H3);
        permute_cvt<<<(GUH * E / 4 + 255) / 256, 256, 0, stream>>>(fold_ff, fold_p, H3, E, 512, GUH * E / 4);
        permute_cvt<<<(GUH * E / 4 + 255) / 256, 256, 0, stream>>>(fold_ff + 256, fold2_p, H3, E, 512, GUH * E / 4);
    }
    // gvb = Wih @ b_iou (the constant the fold2 path drops), permuted
    matvec_f32<<<(GUH + 255) / 256, 256, 0, stream>>>(uh_wih, W_iou_b, gvbr, GUH, H3);
    permute_bias<<<(GUH + 255) / 256, 256, 0, stream>>>(gvbr, gvbu, H3, GUH);

    // ---- leaves (iou in f16) ----
    for (int ls = 0; ls < NLEAF; ls += 4 * C) {
        int Ln = NLEAF - ls < 4 * C ? NLEAF - ls : 4 * C;
        GArg a{};
        a.A0 = embed_h + (size_t)(LEAF0 + ls) * E; a.la0 = E;
        a.B0 = wiou_h; a.lb0 = E; a.K0 = E;
        a.bias = W_iou_b; a.Ch = leaf_h; a.ldc = H3; a.M = Ln; a.N = H3;
        L0(a);
        leaf_apply<<<(Ln * 64 + 255) / 256, 256, 0, stream>>>(
            leaf_h, hbuf_h + (size_t)(LEAF0 + ls) * H, cbuf + (size_t)(LEAF0 + ls) * H, Ln);
    }

    // ---- levels, deepest internal -> root ----
    const int counts[8] = { 1, 4, 16, 64, 256, 1024, 4096, 16384 };
    const int offs[8]   = { 0, 1, 5, 21, 85, 341, 1365, 5461 };
    for (int d = 7; d >= 0; --d) {
        int n = counts[d], start = offs[d];
        for (int s = 0; s < n; s += C) {
            int Cn = n - s < C ? n - s : C;
            int sa = start + s;
            int cst = 4 * sa + 1;

            // x projections: iou | f merged (f16 shadows only)
            {
                GArg u{};
                u.A0 = embed_h + (size_t)sa * E; u.la0 = E;
                u.B0 = wiou_h; u.lb0 = E; u.K0 = E;
                u.bias = W_iou_b; u.Ch = xiou_h; u.ldc = H3;
                u.M = Cn; u.N = H3;
                GArg f = u;
                f.B0 = wf_h; f.bias = W_f_b; f.Ch = xf_h; f.ldc = H; f.N = H;
                P0(u, f);
            }
            // fc messages (GEMM + fc_msg fused; x_f read f16)
            {
                GArg a{};
                a.A0 = hbuf_h + (size_t)cst * H; a.la0 = H;
                a.B0 = uf_h; a.lb0 = H; a.K0 = H;
                a.xff = xf_h; a.cch = cbuf + (size_t)cst * H; a.fcm = fcm_h;
                a.M = 4 * Cn; a.N = H;
                if (a.M >= 8192)
                    gemm_big<2><<<dim3(1, (a.M + 127) / 128), 512, 0, stream>>>(a);
                else
                    gemm_one<2><<<dim3(H / 128, (a.M + 127) / 128), 256, 0, stream>>>(a);
            }
            // 6 LSTM steps; uh | fc merged per step, h double-buffered:
            // step t reads h[(t+1)&1], writes h[t&1]. t=0 (u-side) uses the
            // fold2 path: embed@fold2 (K=E) + gvb == x_iou@Wih; stores tok
            // (f16); t=5 adds it back (K halved), skips dead c-write (fin=1).
            for (int t = 0; t <= 5; ++t) {
                int wb = t & 1, rb = (t + 1) & 1;

                GArg u{};
                u.bias = pbu; u.cb = c_uh; u.hb = huh[wb]; u.HH = H3;
                u.M = Cn; u.N = GUH;
                if (t == 0) {
                    u.A0 = embed_h + (size_t)sa * E; u.la0 = E;
                    u.B0 = fold2_p; u.lb0 = E; u.K0 = E;
                    u.init = 1;
                    u.gst = toku;
                    u.gvb = gvbu;
                } else if (t <= 4) {
                    u.A0 = hbuf_h + (size_t)(cst + t - 1) * H; u.la0 = 4 * H;
                    u.B0 = fold_p; u.lb0 = E; u.K0 = E;
                    u.A1 = huh[rb]; u.la1 = H3; u.B1 = whh_p; u.lb1 = H3; u.K1 = H3;
                } else {
                    u.A0 = huh[rb]; u.la0 = H3; u.B0 = whh_p; u.lb0 = H3; u.K0 = H3;
                    u.gin = toku;
                    u.fin = 1;
                }

                GArg f{};
                f.bias = pbf; f.cb = cfc; f.hb = hfc[wb]; f.HH = H;
                f.M = Cn; f.N = GFC;
                if (t == 0) {
                    f.A0 = xf_h; f.la0 = H; f.B0 = fih_p; f.lb0 = H; f.K0 = H;
                    f.init = 1;
                    f.gst = tokf;
                } else if (t <= 4) {
                    f.A0 = fcm_h + (size_t)(t - 1) * H; f.la0 = 4 * H;
                    f.B0 = fih_p; f.lb0 = H; f.K0 = H;
                    f.A1 = hfc[rb]; f.la1 = H; f.B1 = fhh_p; f.lb1 = H; f.K1 = H;
                } else {
                    f.A0 = hfc[rb]; f.la0 = H; f.B0 = fhh_p; f.lb0 = H; f.K0 = H;
                    f.gin = tokf;
                    f.fin = 1;
                }
                P1(u, f);
            }
            // apply node func (f16 inputs; t=5 wrote huh[1]/hfc[1])
            node_apply<<<(Cn * 64 + 255) / 256, 256, 0, stream>>>(
                xiou_h, huh[1], hfc[1],
                hbuf_h + (size_t)sa * H, cbuf + (size_t)sa * H, Cn);
        }
    }

    // ---- output projection (reads only ws; cbuf is dead) + LN/tanh ----
    {
        GArg a{};
        a.A0 = hbuf_h; a.la0 = H; a.B0 = ow_h; a.lb0 = H; a.K0 = H;
        a.bias = out_b; a.Cf = out; a.ldc = DEC; a.M = NNODES; a.N = DEC;
        L0(a);
    }
    ln_tanh<<<(NNODES + 3) / 4, 256, 0, stream>>>(out, ln_g, ln_b, NNODES);
}